// Round 10
// baseline (209.170 us; speedup 1.0000x reference)
//
#include <hip/hip_runtime.h>
#include <hip/hip_fp16.h>

constexpr int IN_FEATS = 30;
constexpr int HIDDEN   = 64;
constexpr int SCAN_CHUNK = 1024;   // elements per scan block (256 thr x 4)
constexpr int RB_BITS = 9;         // 512 nodes per bucket
constexpr int RB_MASK = (1 << RB_BITS) - 1;
constexpr int ECHUNK  = 2048;      // edges per partition block
// pair packing: (dstLocal << 23) | src  — requires n < 2^23 (here n = 100000)

// ---- partition pass 1: per-chunk LDS bucket histograms for BOTH dst and src ----
__global__ __launch_bounds__(256) void part_count(
    const int* __restrict__ src, const int* __restrict__ dst,
    int* __restrict__ cntT, int nE, int NBK, int NCH, int NK2)
{
    __shared__ int binsD[256], binsS[256];
    int b = blockIdx.x, t = threadIdx.x;
    binsD[t] = 0; binsS[t] = 0;
    __syncthreads();
    int base = b * ECHUNK;
#pragma unroll
    for (int i = 0; i < ECHUNK / 256; ++i) {
        int e = base + t + i * 256;
        if (e < nE) {
            atomicAdd(&binsD[dst[e] >> RB_BITS], 1);
            atomicAdd(&binsS[src[e] >> RB_BITS], 1);
        }
    }
    __syncthreads();
    if (t < NBK) {
        cntT[t * NCH + b]       = binsD[t];
        cntT[NK2 + t * NCH + b] = binsS[t];
    }
}

// ---- multi-block exclusive scan, phase 1: per-block sums ----
__global__ __launch_bounds__(256) void scan_partial(
    const int* __restrict__ deg, int* __restrict__ blockSum, int n)
{
    __shared__ int part[256];
    int b = blockIdx.x, t = threadIdx.x;
    int base = b * SCAN_CHUNK + t * 4;
    int s = 0;
#pragma unroll
    for (int j = 0; j < 4; ++j) { int i = base + j; if (i < n) s += deg[i]; }
    part[t] = s;
    __syncthreads();
    for (int off = 1; off < 256; off <<= 1) {
        int add = (t >= off) ? part[t - off] : 0;
        __syncthreads();
        part[t] += add;
        __syncthreads();
    }
    if (t == 255) blockSum[b] = part[255];
}

// ---- phase 2: exclusive scan of block sums (1 block; nB <= 1024) ----
__global__ __launch_bounds__(1024) void scan_offsets(int* blockSum, int nB, int* totalPtr)
{
    __shared__ int part[1024];
    int t = threadIdx.x;
    int v = (t < nB) ? blockSum[t] : 0;
    part[t] = v;
    __syncthreads();
    for (int off = 1; off < 1024; off <<= 1) {
        int add = (t >= off) ? part[t - off] : 0;
        __syncthreads();
        part[t] += add;
        __syncthreads();
    }
    if (t < nB) blockSum[t] = part[t] - v;   // exclusive block offset
    if (totalPtr && t == nB - 1) *totalPtr = part[t];
}

// ---- phase 3: rescan chunk, write exclusive start offsets ----
__global__ __launch_bounds__(256) void scan_final(
    const int* __restrict__ deg, const int* __restrict__ blockSum,
    int* __restrict__ outp, int n)
{
    __shared__ int part[256];
    int b = blockIdx.x, t = threadIdx.x;
    int base = b * SCAN_CHUNK + t * 4;
    int v[4];
    int s = 0;
#pragma unroll
    for (int j = 0; j < 4; ++j) { int i = base + j; v[j] = (i < n) ? deg[i] : 0; s += v[j]; }
    part[t] = s;
    __syncthreads();
    for (int off = 1; off < 256; off <<= 1) {
        int add = (t >= off) ? part[t - off] : 0;
        __syncthreads();
        part[t] += add;
        __syncthreads();
    }
    int run = blockSum[b] + part[t] - s;
#pragma unroll
    for (int j = 0; j < 4; ++j) {
        int i = base + j;
        if (i < n) outp[i] = run;
        run += v[j];
    }
}

// ---- partition pass 2 (merged): dst LDS counting sort -> packed pairs,
//      plus src scatter -> 16-bit local ids. Reads src/dst exactly once. ----
__global__ __launch_bounds__(256) void part_scatter(
    const int* __restrict__ src, const int* __restrict__ dst,
    const int* __restrict__ ofsT, unsigned int* __restrict__ pairs,
    unsigned short* __restrict__ sloc, int nE, int NBK, int NCH, int NK2)
{
    __shared__ int bins[256], lstart[256], lcur[256], gofs[256], part[256], scur[256];
    __shared__ int lsrc[ECHUNK], ldst[ECHUNK];
    int b = blockIdx.x, t = threadIdx.x;
    bins[t] = 0;
    if (t < NBK) {
        gofs[t] = ofsT[t * NCH + b];
        scur[t] = ofsT[NK2 + t * NCH + b] - nE;   // src offsets live at [nE..2nE)
    }
    __syncthreads();
    int base = b * ECHUNK;
    int rs[ECHUNK / 256], rd[ECHUNK / 256];
#pragma unroll
    for (int i = 0; i < ECHUNK / 256; ++i) {
        int e = base + t + i * 256;
        rs[i] = -1;
        if (e < nE) {
            rs[i] = src[e]; rd[i] = dst[e];
            atomicAdd(&bins[rd[i] >> RB_BITS], 1);
        }
    }
    // src-side scatter (independent of dst sort; scur init'd before first sync)
#pragma unroll
    for (int i = 0; i < ECHUNK / 256; ++i) {
        if (rs[i] >= 0) {
            int s = rs[i];
            int pos = atomicAdd(&scur[s >> RB_BITS], 1);
            sloc[pos] = (unsigned short)(s & RB_MASK);
        }
    }
    __syncthreads();
    int v = bins[t];
    part[t] = v;
    __syncthreads();
    for (int off = 1; off < 256; off <<= 1) {
        int add = (t >= off) ? part[t - off] : 0;
        __syncthreads();
        part[t] += add;
        __syncthreads();
    }
    lstart[t] = part[t] - v;
    lcur[t]   = part[t] - v;
    __syncthreads();
#pragma unroll
    for (int i = 0; i < ECHUNK / 256; ++i) {
        if (rs[i] >= 0) {
            int k = rd[i] >> RB_BITS;
            int p = atomicAdd(&lcur[k], 1);
            lsrc[p] = rs[i]; ldst[p] = rd[i];
        }
    }
    __syncthreads();
    int cE = min(ECHUNK, nE - base);
    for (int j = t; j < cE; j += 256) {
        int d = ldst[j], k = d >> RB_BITS;
        int g = gofs[k] + (j - lstart[k]);
        pairs[g] = ((unsigned int)(d & RB_MASK) << 23) | (unsigned int)lsrc[j];
    }
}

// ---- fused dst-side bucket build: hist -> LDS scan -> degI/rowptr -> csr scatter ----
__global__ __launch_bounds__(256) void bucket_build(
    const unsigned int* __restrict__ pairs, const int* __restrict__ ofsT,
    int* __restrict__ degI, int* __restrict__ rowptr, int* __restrict__ csr,
    int nE, int n, int NBK, int NCH)
{
    __shared__ int bins[512];
    __shared__ int part[256];
    __shared__ int cur[512];
    int k = blockIdx.x, t = threadIdx.x;
    bins[t] = 0; bins[t + 256] = 0;
    __syncthreads();
    int begin = ofsT[k * NCH];
    int end   = (k + 1 < NBK) ? ofsT[(k + 1) * NCH] : nE;
    for (int e = begin + t; e < end; e += 256)
        atomicAdd(&bins[pairs[e] >> 23], 1);
    __syncthreads();
    int v0 = bins[2 * t], v1 = bins[2 * t + 1];
    int s = v0 + v1;
    part[t] = s;
    __syncthreads();
    for (int off = 1; off < 256; off <<= 1) {
        int add = (t >= off) ? part[t - off] : 0;
        __syncthreads();
        part[t] += add;
        __syncthreads();
    }
    int pre = part[t] - s;                 // exclusive prefix within bucket
    int base = k << RB_BITS;
    int n0 = base + 2 * t, n1 = n0 + 1;
    int r0 = begin + pre, r1 = r0 + v0;
    cur[2 * t] = r0; cur[2 * t + 1] = r1;
    if (n0 < n) { degI[n0] = v0; rowptr[n0] = r0; }
    if (n1 < n) { degI[n1] = v1; rowptr[n1] = r1; }
    if (k == NBK - 1 && t == 0) rowptr[n] = nE;
    __syncthreads();
    for (int e = begin + t; e < end; e += 256) {
        unsigned int u = pairs[e];
        int p = atomicAdd(&cur[u >> 23], 1);
        csr[p] = (int)(u & 0x7FFFFFu);
    }
}

// ---- fused src-side: degO hist + xn pack (xn[u] = fp16(x[u] * rsqrt(degO)), pad 32) ----
__global__ __launch_bounds__(256) void bucket_srcside(
    const unsigned short* __restrict__ sloc, const int* __restrict__ ofsT,
    const float* __restrict__ x, int* __restrict__ degO,
    unsigned int* __restrict__ xn, int nE, int n, int NBK, int NCH, int NK2)
{
    __shared__ int bins[512];
    int k = blockIdx.x, t = threadIdx.x;
    bins[t] = 0; bins[t + 256] = 0;
    __syncthreads();
    int begin = ofsT[NK2 + k * NCH] - nE;
    int end   = (k + 1 < NBK) ? (ofsT[NK2 + (k + 1) * NCH] - nE) : nE;
    for (int e = begin + t; e < end; e += 256)
        atomicAdd(&bins[sloc[e]], 1);
    __syncthreads();
    int base = k << RB_BITS;
    if (base + t < n)       degO[base + t]       = bins[t];
    if (base + 256 + t < n) degO[base + 256 + t] = bins[t + 256];
    // pack xn for this bucket's nodes: 512 nodes x 16 half2 words
#pragma unroll 4
    for (int i = 0; i < 32; ++i) {
        int idx = t + 256 * i;             // 0..8191
        int nl = idx >> 4, p = idx & 15;
        int node = base + nl;
        if (node < n) {
            float ns = rsqrtf(fmaxf((float)bins[nl], 1.0f));
            float a = (2 * p     < IN_FEATS) ? x[(size_t)node * IN_FEATS + 2 * p]     * ns : 0.0f;
            float b = (2 * p + 1 < IN_FEATS) ? x[(size_t)node * IN_FEATS + 2 * p + 1] * ns : 0.0f;
            __half2 h = __floats2half2_rn(a, b);
            xn[(size_t)node * 16 + p] = *reinterpret_cast<unsigned int*>(&h);
        }
    }
}

// ---- FUSED layer 1: gather (16 slots/wave, uint4) + register-blocked GEMM ----
// Per block: 4 waves x 8 nodes. Wave gathers node rows into LDS; block GEMMs.
// h1s[v] = fp16(relu((sum_rows @ W1) * nd + b1) * ns), packed x2.
__global__ __launch_bounds__(256) void gx_fused(
    const unsigned int* __restrict__ xn, const int* __restrict__ csr,
    const int* __restrict__ rowptr, const float* __restrict__ W1,
    const float* __restrict__ b1, const int* __restrict__ degI,
    const int* __restrict__ degO, unsigned int* __restrict__ h1s, int n)
{
    __shared__ float w[32 * HIDDEN];       // 8 KB (rows 30..31 zero)
    __shared__ float rows[32][32];         // 4 KB
    int t = threadIdx.x;
    int node0 = blockIdx.x * 32;
    {   // stage W1 (480 float4 + zero pad to 512)
        const float4* w4 = (const float4*)W1;
        float4* lw4 = (float4*)w;
#pragma unroll
        for (int i = 0; i < 2; ++i) {
            int idx = t + 256 * i;
            if (idx < 480)      lw4[idx] = w4[idx];
            else if (idx < 512) lw4[idx] = make_float4(0.f, 0.f, 0.f, 0.f);
        }
    }
    int lane = t & 63, wid = t >> 6;
    int gs = lane >> 2;       // edge slot 0..15
    int p  = lane & 3;        // uint4 index (feats 8p..8p+7)
    for (int j = 0; j < 8; ++j) {
        int slot = wid * 8 + j;
        int node = node0 + slot;
        if (node < n) {
            int begin = rowptr[node], end = rowptr[node + 1];
            float a0 = 0, a1 = 0, a2 = 0, a3 = 0, a4 = 0, a5 = 0, a6 = 0, a7 = 0;
            int e = begin + gs;
            for (; e + 16 < end; e += 32) {
                int s0 = csr[e], s1 = csr[e + 16];
                uint4 u0 = *reinterpret_cast<const uint4*>(xn + (size_t)s0 * 16 + 4 * p);
                uint4 u1 = *reinterpret_cast<const uint4*>(xn + (size_t)s1 * 16 + 4 * p);
                float2 v;
                v = __half22float2(*reinterpret_cast<__half2*>(&u0.x)); a0 += v.x; a1 += v.y;
                v = __half22float2(*reinterpret_cast<__half2*>(&u0.y)); a2 += v.x; a3 += v.y;
                v = __half22float2(*reinterpret_cast<__half2*>(&u0.z)); a4 += v.x; a5 += v.y;
                v = __half22float2(*reinterpret_cast<__half2*>(&u0.w)); a6 += v.x; a7 += v.y;
                v = __half22float2(*reinterpret_cast<__half2*>(&u1.x)); a0 += v.x; a1 += v.y;
                v = __half22float2(*reinterpret_cast<__half2*>(&u1.y)); a2 += v.x; a3 += v.y;
                v = __half22float2(*reinterpret_cast<__half2*>(&u1.z)); a4 += v.x; a5 += v.y;
                v = __half22float2(*reinterpret_cast<__half2*>(&u1.w)); a6 += v.x; a7 += v.y;
            }
            if (e < end) {
                int s0 = csr[e];
                uint4 u0 = *reinterpret_cast<const uint4*>(xn + (size_t)s0 * 16 + 4 * p);
                float2 v;
                v = __half22float2(*reinterpret_cast<__half2*>(&u0.x)); a0 += v.x; a1 += v.y;
                v = __half22float2(*reinterpret_cast<__half2*>(&u0.y)); a2 += v.x; a3 += v.y;
                v = __half22float2(*reinterpret_cast<__half2*>(&u0.z)); a4 += v.x; a5 += v.y;
                v = __half22float2(*reinterpret_cast<__half2*>(&u0.w)); a6 += v.x; a7 += v.y;
            }
#pragma unroll
            for (int m = 4; m <= 32; m <<= 1) {
                a0 += __shfl_xor(a0, m); a1 += __shfl_xor(a1, m);
                a2 += __shfl_xor(a2, m); a3 += __shfl_xor(a3, m);
                a4 += __shfl_xor(a4, m); a5 += __shfl_xor(a5, m);
                a6 += __shfl_xor(a6, m); a7 += __shfl_xor(a7, m);
            }
            if (gs == 0) {
                *reinterpret_cast<float4*>(&rows[slot][8 * p])     = make_float4(a0, a1, a2, a3);
                *reinterpret_cast<float4*>(&rows[slot][8 * p + 4]) = make_float4(a4, a5, a6, a7);
            }
        }
    }
    __syncthreads();
    // register-blocked GEMM: thread (f,g) computes out col f for nodes g*8..g*8+7
    int f = t & 63, g = t >> 6;
    float acc[8] = {0, 0, 0, 0, 0, 0, 0, 0};
#pragma unroll 2
    for (int k = 0; k < 32; k += 4) {
        float w0 = w[(k + 0) * 64 + f], w1 = w[(k + 1) * 64 + f];
        float w2v = w[(k + 2) * 64 + f], w3 = w[(k + 3) * 64 + f];
#pragma unroll
        for (int j = 0; j < 8; ++j) {
            float4 rv = *reinterpret_cast<const float4*>(&rows[g * 8 + j][k]);
            acc[j] = fmaf(rv.x, w0, acc[j]);
            acc[j] = fmaf(rv.y, w1, acc[j]);
            acc[j] = fmaf(rv.z, w2v, acc[j]);
            acc[j] = fmaf(rv.w, w3, acc[j]);
        }
    }
    float bv = b1[f];
#pragma unroll
    for (int j = 0; j < 8; ++j) {
        int node = node0 + g * 8 + j;
        float hv = 0.0f;
        if (node < n) {
            float ndv = rsqrtf(fmaxf((float)degI[node], 1.0f));
            float nsv = rsqrtf(fmaxf((float)degO[node], 1.0f));
            hv = fmaxf(fmaf(acc[j], ndv, bv), 0.0f) * nsv;
        }
        float hv1 = __shfl_down(hv, 1);
        if (node < n && (f & 1) == 0) {
            __half2 h = __floats2half2_rn(hv, hv1);
            h1s[(size_t)node * 32 + (f >> 1)] = *reinterpret_cast<unsigned int*>(&h);
        }
    }
}

// ---- FUSED layer 2: gather (8 slots/wave, uint4) + register-blocked GEMM ----
// out[v] = relu((sum_rows @ W2) * nd + b2), written straight to d_out.
__global__ __launch_bounds__(256) void gh_fused(
    const unsigned int* __restrict__ h, const int* __restrict__ csr,
    const int* __restrict__ rowptr, const float* __restrict__ W2,
    const float* __restrict__ b2, const int* __restrict__ degI,
    float* __restrict__ out, int n)
{
    __shared__ float w[HIDDEN * HIDDEN];   // 16 KB
    __shared__ float rows[32][HIDDEN];     // 8 KB
    int t = threadIdx.x;
    int node0 = blockIdx.x * 32;
    {   // stage W2 (1024 float4)
        const float4* w4 = (const float4*)W2;
        float4* lw4 = (float4*)w;
#pragma unroll
        for (int i = 0; i < 4; ++i) lw4[t + 256 * i] = w4[t + 256 * i];
    }
    int lane = t & 63, wid = t >> 6;
    int gs = lane >> 3;       // edge slot 0..7
    int p  = lane & 7;        // uint4 index (feats 8p..8p+7)
    for (int j = 0; j < 8; ++j) {
        int slot = wid * 8 + j;
        int node = node0 + slot;
        if (node < n) {
            int begin = rowptr[node], end = rowptr[node + 1];
            float a0 = 0, a1 = 0, a2 = 0, a3 = 0, a4 = 0, a5 = 0, a6 = 0, a7 = 0;
            int e = begin + gs;
            for (; e + 8 < end; e += 16) {
                int s0 = csr[e], s1 = csr[e + 8];
                uint4 u0 = *reinterpret_cast<const uint4*>(h + (size_t)s0 * 32 + 4 * p);
                uint4 u1 = *reinterpret_cast<const uint4*>(h + (size_t)s1 * 32 + 4 * p);
                float2 v;
                v = __half22float2(*reinterpret_cast<__half2*>(&u0.x)); a0 += v.x; a1 += v.y;
                v = __half22float2(*reinterpret_cast<__half2*>(&u0.y)); a2 += v.x; a3 += v.y;
                v = __half22float2(*reinterpret_cast<__half2*>(&u0.z)); a4 += v.x; a5 += v.y;
                v = __half22float2(*reinterpret_cast<__half2*>(&u0.w)); a6 += v.x; a7 += v.y;
                v = __half22float2(*reinterpret_cast<__half2*>(&u1.x)); a0 += v.x; a1 += v.y;
                v = __half22float2(*reinterpret_cast<__half2*>(&u1.y)); a2 += v.x; a3 += v.y;
                v = __half22float2(*reinterpret_cast<__half2*>(&u1.z)); a4 += v.x; a5 += v.y;
                v = __half22float2(*reinterpret_cast<__half2*>(&u1.w)); a6 += v.x; a7 += v.y;
            }
            if (e < end) {
                int s0 = csr[e];
                uint4 u0 = *reinterpret_cast<const uint4*>(h + (size_t)s0 * 32 + 4 * p);
                float2 v;
                v = __half22float2(*reinterpret_cast<__half2*>(&u0.x)); a0 += v.x; a1 += v.y;
                v = __half22float2(*reinterpret_cast<__half2*>(&u0.y)); a2 += v.x; a3 += v.y;
                v = __half22float2(*reinterpret_cast<__half2*>(&u0.z)); a4 += v.x; a5 += v.y;
                v = __half22float2(*reinterpret_cast<__half2*>(&u0.w)); a6 += v.x; a7 += v.y;
            }
#pragma unroll
            for (int m = 8; m <= 32; m <<= 1) {
                a0 += __shfl_xor(a0, m); a1 += __shfl_xor(a1, m);
                a2 += __shfl_xor(a2, m); a3 += __shfl_xor(a3, m);
                a4 += __shfl_xor(a4, m); a5 += __shfl_xor(a5, m);
                a6 += __shfl_xor(a6, m); a7 += __shfl_xor(a7, m);
            }
            if (gs == 0) {
                *reinterpret_cast<float4*>(&rows[slot][8 * p])     = make_float4(a0, a1, a2, a3);
                *reinterpret_cast<float4*>(&rows[slot][8 * p + 4]) = make_float4(a4, a5, a6, a7);
            }
        }
    }
    __syncthreads();
    int f = t & 63, g = t >> 6;
    float acc[8] = {0, 0, 0, 0, 0, 0, 0, 0};
#pragma unroll 2
    for (int k = 0; k < 64; k += 4) {
        float w0 = w[(k + 0) * 64 + f], w1 = w[(k + 1) * 64 + f];
        float w2v = w[(k + 2) * 64 + f], w3 = w[(k + 3) * 64 + f];
#pragma unroll
        for (int j = 0; j < 8; ++j) {
            float4 rv = *reinterpret_cast<const float4*>(&rows[g * 8 + j][k]);
            acc[j] = fmaf(rv.x, w0, acc[j]);
            acc[j] = fmaf(rv.y, w1, acc[j]);
            acc[j] = fmaf(rv.z, w2v, acc[j]);
            acc[j] = fmaf(rv.w, w3, acc[j]);
        }
    }
    float bv = b2[f];
#pragma unroll
    for (int j = 0; j < 8; ++j) {
        int node = node0 + g * 8 + j;
        if (node < n) {
            float ndv = rsqrtf(fmaxf((float)degI[node], 1.0f));
            out[(size_t)node * 64 + f] = fmaxf(fmaf(acc[j], ndv, bv), 0.0f);
        }
    }
}

extern "C" void kernel_launch(void* const* d_in, const int* in_sizes, int n_in,
                              void* d_out, int out_size, void* d_ws, size_t ws_size,
                              hipStream_t stream)
{
    const float* x  = (const float*)d_in[0];
    const float* W1 = (const float*)d_in[1];
    const float* b1 = (const float*)d_in[2];
    const float* W2 = (const float*)d_in[3];
    const float* b2 = (const float*)d_in[4];
    const int*  src = (const int*)d_in[5];
    const int*  dst = (const int*)d_in[6];
    float* out = (float*)d_out;

    const int n  = in_sizes[0] / IN_FEATS;   // 100000
    const int nE = in_sizes[5];              // 1200000

    const int NBK = (n + (1 << RB_BITS) - 1) >> RB_BITS;     // 196 buckets (<=256)
    const int NCH = (nE + ECHUNK - 1) / ECHUNK;              // 586 chunks
    const int NK2 = NBK * NCH;

    // workspace layout (non-aliased):
    // pairs[nE] | cntT[2*NK2] | bsum[1024] | sloc[nE u16] | xn[n*16] | h1s[n*32] |
    // degO[n] | degI[n] | rowptr[n+1] | csr[nE]
    unsigned int* pairs = (unsigned int*)d_ws;
    int* cntT = (int*)d_ws + nE;
    int* bsum = cntT + 2 * NK2;
    unsigned short* sloc = (unsigned short*)(bsum + 1024);
    unsigned int* xn  = (unsigned int*)(bsum + 1024) + (nE + 1) / 2;
    unsigned int* h1s = xn + (size_t)n * 16;
    int* degO   = (int*)(h1s + (size_t)n * 32);
    int* degI   = degO + n;
    int* rowptr = degI + n;
    int* csr    = rowptr + (n + 1);

    const int nB2 = (2 * NK2 + SCAN_CHUNK - 1) / SCAN_CHUNK;     // combined cntT scan
    const int fusedBlocks = (n + 31) / 32;

    // combined dst+src bucket counts -> one scan over 2*NK2 -> in-place offsets
    part_count<<<NCH, 256, 0, stream>>>(src, dst, cntT, nE, NBK, NCH, NK2);
    scan_partial<<<nB2, 256, 0, stream>>>(cntT, bsum, 2 * NK2);
    scan_offsets<<<1, 1024, 0, stream>>>(bsum, nB2, nullptr);
    scan_final<<<nB2, 256, 0, stream>>>(cntT, bsum, cntT, 2 * NK2);

    // single partition pass: packed dst pairs + src local ids
    part_scatter<<<NCH, 256, 0, stream>>>(src, dst, cntT, pairs, sloc, nE, NBK, NCH, NK2);

    // fused bucket kernels: dst side (degI+rowptr+csr), src side (degO+xn)
    bucket_build<<<NBK, 256, 0, stream>>>(pairs, cntT, degI, rowptr, csr, nE, n, NBK, NCH);
    bucket_srcside<<<NBK, 256, 0, stream>>>(sloc, cntT, x, degO, xn, nE, n, NBK, NCH, NK2);

    // layer 1 fused: gather xn + transform -> h1s (fp16)
    gx_fused<<<fusedBlocks, 256, 0, stream>>>(xn, csr, rowptr, W1, b1, degI, degO, h1s, n);

    // layer 2 fused: gather h1s + transform -> d_out
    gh_fused<<<fusedBlocks, 256, 0, stream>>>(h1s, csr, rowptr, W2, b2, degI, out, n);
}

// Round 11
// 201.339 us; speedup vs baseline: 1.0389x; 1.0389x over previous
//
#include <hip/hip_runtime.h>
#include <hip/hip_fp16.h>

constexpr int IN_FEATS = 30;
constexpr int HIDDEN   = 64;
constexpr int SCAN_CHUNK = 1024;   // elements per scan block (256 thr x 4)
constexpr int RB_BITS = 9;         // 512 nodes per bucket
constexpr int RB_MASK = (1 << RB_BITS) - 1;
constexpr int ECHUNK  = 4096;      // edges per partition block
constexpr int NPB     = 32;        // nodes per transform block
// pair packing: (dstLocal << 23) | src  — requires n < 2^23 (here n = 100000)

// ---- partition pass 1: per-chunk LDS bucket histograms for BOTH dst and src ----
__global__ __launch_bounds__(256) void part_count(
    const int* __restrict__ src, const int* __restrict__ dst,
    int* __restrict__ cntT, int nE, int NBK, int NCH, int NK2)
{
    __shared__ int binsD[256], binsS[256];
    int b = blockIdx.x, t = threadIdx.x;
    binsD[t] = 0; binsS[t] = 0;
    __syncthreads();
    int base = b * ECHUNK;
#pragma unroll
    for (int i = 0; i < ECHUNK / 256; ++i) {
        int e = base + t + i * 256;
        if (e < nE) {
            atomicAdd(&binsD[dst[e] >> RB_BITS], 1);
            atomicAdd(&binsS[src[e] >> RB_BITS], 1);
        }
    }
    __syncthreads();
    if (t < NBK) {
        cntT[t * NCH + b]       = binsD[t];
        cntT[NK2 + t * NCH + b] = binsS[t];
    }
}

// ---- multi-block exclusive scan, phase 1: per-block sums ----
__global__ __launch_bounds__(256) void scan_partial(
    const int* __restrict__ deg, int* __restrict__ blockSum, int n)
{
    __shared__ int part[256];
    int b = blockIdx.x, t = threadIdx.x;
    int base = b * SCAN_CHUNK + t * 4;
    int s = 0;
#pragma unroll
    for (int j = 0; j < 4; ++j) { int i = base + j; if (i < n) s += deg[i]; }
    part[t] = s;
    __syncthreads();
    for (int off = 1; off < 256; off <<= 1) {
        int add = (t >= off) ? part[t - off] : 0;
        __syncthreads();
        part[t] += add;
        __syncthreads();
    }
    if (t == 255) blockSum[b] = part[255];
}

// ---- phase 2: exclusive scan of block sums (1 block; nB <= 1024) ----
__global__ __launch_bounds__(1024) void scan_offsets(int* blockSum, int nB, int* totalPtr)
{
    __shared__ int part[1024];
    int t = threadIdx.x;
    int v = (t < nB) ? blockSum[t] : 0;
    part[t] = v;
    __syncthreads();
    for (int off = 1; off < 1024; off <<= 1) {
        int add = (t >= off) ? part[t - off] : 0;
        __syncthreads();
        part[t] += add;
        __syncthreads();
    }
    if (t < nB) blockSum[t] = part[t] - v;   // exclusive block offset
    if (totalPtr && t == nB - 1) *totalPtr = part[t];
}

// ---- phase 3: rescan chunk, write exclusive start offsets ----
__global__ __launch_bounds__(256) void scan_final(
    const int* __restrict__ deg, const int* __restrict__ blockSum,
    int* __restrict__ outp, int n)
{
    __shared__ int part[256];
    int b = blockIdx.x, t = threadIdx.x;
    int base = b * SCAN_CHUNK + t * 4;
    int v[4];
    int s = 0;
#pragma unroll
    for (int j = 0; j < 4; ++j) { int i = base + j; v[j] = (i < n) ? deg[i] : 0; s += v[j]; }
    part[t] = s;
    __syncthreads();
    for (int off = 1; off < 256; off <<= 1) {
        int add = (t >= off) ? part[t - off] : 0;
        __syncthreads();
        part[t] += add;
        __syncthreads();
    }
    int run = blockSum[b] + part[t] - s;
#pragma unroll
    for (int j = 0; j < 4; ++j) {
        int i = base + j;
        if (i < n) outp[i] = run;
        run += v[j];
    }
}

// ---- partition pass 2: direct scatter via per-(bucket,chunk) LDS cursors.
//      No counting sort: pairs/sloc order within a bucket is irrelevant
//      (consumers are histograms + cursor scatter). ----
__global__ __launch_bounds__(256) void part_scatter(
    const int* __restrict__ src, const int* __restrict__ dst,
    const int* __restrict__ ofsT, unsigned int* __restrict__ pairs,
    unsigned short* __restrict__ sloc, int nE, int NBK, int NCH, int NK2)
{
    __shared__ int curD[256], curS[256];
    int b = blockIdx.x, t = threadIdx.x;
    if (t < NBK) {
        curD[t] = ofsT[t * NCH + b];
        curS[t] = ofsT[NK2 + t * NCH + b] - nE;   // src offsets live at [nE..2nE)
    }
    __syncthreads();
    int base = b * ECHUNK;
#pragma unroll
    for (int i = 0; i < ECHUNK / 256; ++i) {
        int e = base + t + i * 256;
        if (e < nE) {
            int s = src[e], d = dst[e];
            int pD = atomicAdd(&curD[d >> RB_BITS], 1);
            pairs[pD] = ((unsigned int)(d & RB_MASK) << 23) | (unsigned int)s;
            int pS = atomicAdd(&curS[s >> RB_BITS], 1);
            sloc[pS] = (unsigned short)(s & RB_MASK);
        }
    }
}

// ---- fused dst-side bucket build: hist -> LDS scan -> degI/rowptr -> csr scatter ----
__global__ __launch_bounds__(256) void bucket_build(
    const unsigned int* __restrict__ pairs, const int* __restrict__ ofsT,
    int* __restrict__ degI, int* __restrict__ rowptr, int* __restrict__ csr,
    int nE, int n, int NBK, int NCH)
{
    __shared__ int bins[512];
    __shared__ int part[256];
    __shared__ int cur[512];
    int k = blockIdx.x, t = threadIdx.x;
    bins[t] = 0; bins[t + 256] = 0;
    __syncthreads();
    int begin = ofsT[k * NCH];
    int end   = (k + 1 < NBK) ? ofsT[(k + 1) * NCH] : nE;
    for (int e = begin + t; e < end; e += 256)
        atomicAdd(&bins[pairs[e] >> 23], 1);
    __syncthreads();
    int v0 = bins[2 * t], v1 = bins[2 * t + 1];
    int s = v0 + v1;
    part[t] = s;
    __syncthreads();
    for (int off = 1; off < 256; off <<= 1) {
        int add = (t >= off) ? part[t - off] : 0;
        __syncthreads();
        part[t] += add;
        __syncthreads();
    }
    int pre = part[t] - s;                 // exclusive prefix within bucket
    int base = k << RB_BITS;
    int n0 = base + 2 * t, n1 = n0 + 1;
    int r0 = begin + pre, r1 = r0 + v0;
    cur[2 * t] = r0; cur[2 * t + 1] = r1;
    if (n0 < n) { degI[n0] = v0; rowptr[n0] = r0; }
    if (n1 < n) { degI[n1] = v1; rowptr[n1] = r1; }
    if (k == NBK - 1 && t == 0) rowptr[n] = nE;
    __syncthreads();
    for (int e = begin + t; e < end; e += 256) {
        unsigned int u = pairs[e];
        int p = atomicAdd(&cur[u >> 23], 1);
        csr[p] = (int)(u & 0x7FFFFFu);
    }
}

// ---- fused src-side: degO hist + xn pack (xn[u] = fp16(x[u] * rsqrt(degO)), pad 32) ----
__global__ __launch_bounds__(256) void bucket_srcside(
    const unsigned short* __restrict__ sloc, const int* __restrict__ ofsT,
    const float* __restrict__ x, int* __restrict__ degO,
    unsigned int* __restrict__ xn, int nE, int n, int NBK, int NCH, int NK2)
{
    __shared__ int bins[512];
    int k = blockIdx.x, t = threadIdx.x;
    bins[t] = 0; bins[t + 256] = 0;
    __syncthreads();
    int begin = ofsT[NK2 + k * NCH] - nE;
    int end   = (k + 1 < NBK) ? (ofsT[NK2 + (k + 1) * NCH] - nE) : nE;
    for (int e = begin + t; e < end; e += 256)
        atomicAdd(&bins[sloc[e]], 1);
    __syncthreads();
    int base = k << RB_BITS;
    if (base + t < n)       degO[base + t]       = bins[t];
    if (base + 256 + t < n) degO[base + 256 + t] = bins[t + 256];
    // pack xn for this bucket's nodes: 512 nodes x 16 half2 words
#pragma unroll 4
    for (int i = 0; i < 32; ++i) {
        int idx = t + 256 * i;             // 0..8191
        int nl = idx >> 4, p = idx & 15;
        int node = base + nl;
        if (node < n) {
            float ns = rsqrtf(fmaxf((float)bins[nl], 1.0f));
            float a = (2 * p     < IN_FEATS) ? x[(size_t)node * IN_FEATS + 2 * p]     * ns : 0.0f;
            float b = (2 * p + 1 < IN_FEATS) ? x[(size_t)node * IN_FEATS + 2 * p + 1] * ns : 0.0f;
            __half2 h = __floats2half2_rn(a, b);
            xn[(size_t)node * 16 + p] = *reinterpret_cast<unsigned int*>(&h);
        }
    }
}

// ---- layer-1 aggregation: 16 edge slots/wave, uint4 loads (64 B row), 2x unroll ----
__global__ __launch_bounds__(256) void gather_x2(
    const unsigned int* __restrict__ xn, const int* __restrict__ csr,
    const int* __restrict__ rowptr, float* __restrict__ aggx, int n)
{
    int wv   = (blockIdx.x * 256 + threadIdx.x) >> 6;
    int lane = threadIdx.x & 63;
    if (wv >= n) return;
    int begin = rowptr[wv], end = rowptr[wv + 1];
    int g = lane >> 2;        // edge slot 0..15
    int p = lane & 3;         // uint4 index (feat pairs 4p..4p+3)
    float a0 = 0, a1 = 0, a2 = 0, a3 = 0, a4 = 0, a5 = 0, a6 = 0, a7 = 0;
    int e = begin + g;
    for (; e + 16 < end; e += 32) {
        int s0 = csr[e], s1 = csr[e + 16];
        uint4 u0 = *reinterpret_cast<const uint4*>(xn + (size_t)s0 * 16 + 4 * p);
        uint4 u1 = *reinterpret_cast<const uint4*>(xn + (size_t)s1 * 16 + 4 * p);
        float2 v;
        v = __half22float2(*reinterpret_cast<__half2*>(&u0.x)); a0 += v.x; a1 += v.y;
        v = __half22float2(*reinterpret_cast<__half2*>(&u0.y)); a2 += v.x; a3 += v.y;
        v = __half22float2(*reinterpret_cast<__half2*>(&u0.z)); a4 += v.x; a5 += v.y;
        v = __half22float2(*reinterpret_cast<__half2*>(&u0.w)); a6 += v.x; a7 += v.y;
        v = __half22float2(*reinterpret_cast<__half2*>(&u1.x)); a0 += v.x; a1 += v.y;
        v = __half22float2(*reinterpret_cast<__half2*>(&u1.y)); a2 += v.x; a3 += v.y;
        v = __half22float2(*reinterpret_cast<__half2*>(&u1.z)); a4 += v.x; a5 += v.y;
        v = __half22float2(*reinterpret_cast<__half2*>(&u1.w)); a6 += v.x; a7 += v.y;
    }
    if (e < end) {
        int s0 = csr[e];
        uint4 u0 = *reinterpret_cast<const uint4*>(xn + (size_t)s0 * 16 + 4 * p);
        float2 v;
        v = __half22float2(*reinterpret_cast<__half2*>(&u0.x)); a0 += v.x; a1 += v.y;
        v = __half22float2(*reinterpret_cast<__half2*>(&u0.y)); a2 += v.x; a3 += v.y;
        v = __half22float2(*reinterpret_cast<__half2*>(&u0.z)); a4 += v.x; a5 += v.y;
        v = __half22float2(*reinterpret_cast<__half2*>(&u0.w)); a6 += v.x; a7 += v.y;
    }
#pragma unroll
    for (int m = 4; m <= 32; m <<= 1) {
        a0 += __shfl_xor(a0, m); a1 += __shfl_xor(a1, m);
        a2 += __shfl_xor(a2, m); a3 += __shfl_xor(a3, m);
        a4 += __shfl_xor(a4, m); a5 += __shfl_xor(a5, m);
        a6 += __shfl_xor(a6, m); a7 += __shfl_xor(a7, m);
    }
    if (g == 0) {
        *reinterpret_cast<float4*>(aggx + (size_t)wv * 32 + 8 * p)     = make_float4(a0, a1, a2, a3);
        *reinterpret_cast<float4*>(aggx + (size_t)wv * 32 + 8 * p + 4) = make_float4(a4, a5, a6, a7);
    }
}

// ---- layer-1 dense, register-blocked: 32 nodes/block, 8 acc/thread ----
__global__ __launch_bounds__(256) void transform1(
    const float* __restrict__ aggx, const float* __restrict__ W1,
    const float* __restrict__ b1, const int* __restrict__ degI,
    const int* __restrict__ degO, unsigned int* __restrict__ h1s, int n)
{
    __shared__ float w[32 * HIDDEN];       // 8 KB, rows 30..31 zero
    __shared__ float rows[NPB][32];        // 4 KB
    int t = threadIdx.x;
    int node0 = blockIdx.x * NPB;
    {
        const float4* w4 = (const float4*)W1;
        float4* lw4 = (float4*)w;
#pragma unroll
        for (int i = 0; i < 2; ++i) {
            int idx = t + 256 * i;
            if (idx < 480)      lw4[idx] = w4[idx];
            else if (idx < 512) lw4[idx] = make_float4(0.f, 0.f, 0.f, 0.f);
        }
    }
    {
        int node = node0 + (t >> 3);
        if (node < n)
            *reinterpret_cast<float4*>(&rows[t >> 3][(t & 7) * 4]) =
                *reinterpret_cast<const float4*>(aggx + (size_t)node * 32 + (t & 7) * 4);
    }
    __syncthreads();
    int f = t & 63, g = t >> 6;
    float acc[8] = {0, 0, 0, 0, 0, 0, 0, 0};
#pragma unroll 2
    for (int k = 0; k < 32; k += 4) {
        float w0 = w[(k + 0) * 64 + f], w1 = w[(k + 1) * 64 + f];
        float w2v = w[(k + 2) * 64 + f], w3 = w[(k + 3) * 64 + f];
#pragma unroll
        for (int j = 0; j < 8; ++j) {
            float4 rv = *reinterpret_cast<const float4*>(&rows[g * 8 + j][k]);
            acc[j] = fmaf(rv.x, w0, acc[j]);
            acc[j] = fmaf(rv.y, w1, acc[j]);
            acc[j] = fmaf(rv.z, w2v, acc[j]);
            acc[j] = fmaf(rv.w, w3, acc[j]);
        }
    }
    float bv = b1[f];
#pragma unroll
    for (int j = 0; j < 8; ++j) {
        int node = node0 + g * 8 + j;
        float hv = 0.0f;
        if (node < n) {
            float ndv = rsqrtf(fmaxf((float)degI[node], 1.0f));
            float nsv = rsqrtf(fmaxf((float)degO[node], 1.0f));
            hv = fmaxf(fmaf(acc[j], ndv, bv), 0.0f) * nsv;
        }
        float hv1 = __shfl_down(hv, 1);
        if (node < n && (f & 1) == 0) {
            __half2 h = __floats2half2_rn(hv, hv1);
            h1s[(size_t)node * 32 + (f >> 1)] = *reinterpret_cast<unsigned int*>(&h);
        }
    }
}

// ---- layer-2 aggregation: 8 edge slots/wave, uint4 loads (128 B row), 2x unroll ----
__global__ __launch_bounds__(256) void gather_h2(
    const unsigned int* __restrict__ h, const int* __restrict__ csr,
    const int* __restrict__ rowptr, float* __restrict__ agg, int n)
{
    int wv   = (blockIdx.x * 256 + threadIdx.x) >> 6;
    int lane = threadIdx.x & 63;
    if (wv >= n) return;
    int begin = rowptr[wv], end = rowptr[wv + 1];
    int g = lane >> 3;        // edge slot 0..7
    int p = lane & 7;         // uint4 index (feat pairs 4p..4p+3)
    float a0 = 0, a1 = 0, a2 = 0, a3 = 0, a4 = 0, a5 = 0, a6 = 0, a7 = 0;
    int e = begin + g;
    for (; e + 8 < end; e += 16) {
        int s0 = csr[e], s1 = csr[e + 8];
        uint4 u0 = *reinterpret_cast<const uint4*>(h + (size_t)s0 * 32 + 4 * p);
        uint4 u1 = *reinterpret_cast<const uint4*>(h + (size_t)s1 * 32 + 4 * p);
        float2 v;
        v = __half22float2(*reinterpret_cast<__half2*>(&u0.x)); a0 += v.x; a1 += v.y;
        v = __half22float2(*reinterpret_cast<__half2*>(&u0.y)); a2 += v.x; a3 += v.y;
        v = __half22float2(*reinterpret_cast<__half2*>(&u0.z)); a4 += v.x; a5 += v.y;
        v = __half22float2(*reinterpret_cast<__half2*>(&u0.w)); a6 += v.x; a7 += v.y;
        v = __half22float2(*reinterpret_cast<__half2*>(&u1.x)); a0 += v.x; a1 += v.y;
        v = __half22float2(*reinterpret_cast<__half2*>(&u1.y)); a2 += v.x; a3 += v.y;
        v = __half22float2(*reinterpret_cast<__half2*>(&u1.z)); a4 += v.x; a5 += v.y;
        v = __half22float2(*reinterpret_cast<__half2*>(&u1.w)); a6 += v.x; a7 += v.y;
    }
    if (e < end) {
        int s0 = csr[e];
        uint4 u0 = *reinterpret_cast<const uint4*>(h + (size_t)s0 * 32 + 4 * p);
        float2 v;
        v = __half22float2(*reinterpret_cast<__half2*>(&u0.x)); a0 += v.x; a1 += v.y;
        v = __half22float2(*reinterpret_cast<__half2*>(&u0.y)); a2 += v.x; a3 += v.y;
        v = __half22float2(*reinterpret_cast<__half2*>(&u0.z)); a4 += v.x; a5 += v.y;
        v = __half22float2(*reinterpret_cast<__half2*>(&u0.w)); a6 += v.x; a7 += v.y;
    }
#pragma unroll
    for (int m = 8; m <= 32; m <<= 1) {
        a0 += __shfl_xor(a0, m); a1 += __shfl_xor(a1, m);
        a2 += __shfl_xor(a2, m); a3 += __shfl_xor(a3, m);
        a4 += __shfl_xor(a4, m); a5 += __shfl_xor(a5, m);
        a6 += __shfl_xor(a6, m); a7 += __shfl_xor(a7, m);
    }
    if (g == 0) {
        *reinterpret_cast<float4*>(agg + (size_t)wv * 64 + 8 * p)     = make_float4(a0, a1, a2, a3);
        *reinterpret_cast<float4*>(agg + (size_t)wv * 64 + 8 * p + 4) = make_float4(a4, a5, a6, a7);
    }
}

// ---- layer-2 dense, register-blocked, in place on d_out ----
__global__ __launch_bounds__(256) void transform2(
    float* aggout, const float* __restrict__ W2,
    const float* __restrict__ b2, const int* __restrict__ degI, int n)
{
    __shared__ float w[HIDDEN * HIDDEN];   // 16 KB
    __shared__ float rows[NPB][HIDDEN];    // 8 KB
    int t = threadIdx.x;
    int node0 = blockIdx.x * NPB;
    {
        const float4* w4 = (const float4*)W2;
        float4* lw4 = (float4*)w;
#pragma unroll
        for (int i = 0; i < 4; ++i) lw4[t + 256 * i] = w4[t + 256 * i];
    }
    {
#pragma unroll
        for (int i = 0; i < 2; ++i) {
            int idx = t + 256 * i;
            int node = node0 + (idx >> 4);
            if (node < n)
                *reinterpret_cast<float4*>(&rows[idx >> 4][(idx & 15) * 4]) =
                    *reinterpret_cast<const float4*>(aggout + (size_t)node * 64 + (idx & 15) * 4);
        }
    }
    __syncthreads();
    int f = t & 63, g = t >> 6;
    float acc[8] = {0, 0, 0, 0, 0, 0, 0, 0};
#pragma unroll 2
    for (int k = 0; k < 64; k += 4) {
        float w0 = w[(k + 0) * 64 + f], w1 = w[(k + 1) * 64 + f];
        float w2v = w[(k + 2) * 64 + f], w3 = w[(k + 3) * 64 + f];
#pragma unroll
        for (int j = 0; j < 8; ++j) {
            float4 rv = *reinterpret_cast<const float4*>(&rows[g * 8 + j][k]);
            acc[j] = fmaf(rv.x, w0, acc[j]);
            acc[j] = fmaf(rv.y, w1, acc[j]);
            acc[j] = fmaf(rv.z, w2v, acc[j]);
            acc[j] = fmaf(rv.w, w3, acc[j]);
        }
    }
    float bv = b2[f];
#pragma unroll
    for (int j = 0; j < 8; ++j) {
        int node = node0 + g * 8 + j;
        if (node < n) {
            float ndv = rsqrtf(fmaxf((float)degI[node], 1.0f));
            aggout[(size_t)node * 64 + f] = fmaxf(fmaf(acc[j], ndv, bv), 0.0f);
        }
    }
}

extern "C" void kernel_launch(void* const* d_in, const int* in_sizes, int n_in,
                              void* d_out, int out_size, void* d_ws, size_t ws_size,
                              hipStream_t stream)
{
    const float* x  = (const float*)d_in[0];
    const float* W1 = (const float*)d_in[1];
    const float* b1 = (const float*)d_in[2];
    const float* W2 = (const float*)d_in[3];
    const float* b2 = (const float*)d_in[4];
    const int*  src = (const int*)d_in[5];
    const int*  dst = (const int*)d_in[6];
    float* out = (float*)d_out;

    const int n  = in_sizes[0] / IN_FEATS;   // 100000
    const int nE = in_sizes[5];              // 1200000

    const int NBK = (n + (1 << RB_BITS) - 1) >> RB_BITS;     // 196 buckets (<=256)
    const int NCH = (nE + ECHUNK - 1) / ECHUNK;              // 293 chunks
    const int NK2 = NBK * NCH;

    // workspace layout (non-aliased, ~33 MB):
    // pairs[nE] | cntT[2*NK2] | bsum[1024] | sloc[nE u16] | xn[n*16] | h1s[n*32] |
    // degO[n] | degI[n] | rowptr[n+1] | csr[nE]
    unsigned int* pairs = (unsigned int*)d_ws;
    int* cntT = (int*)d_ws + nE;
    int* bsum = cntT + 2 * NK2;
    unsigned short* sloc = (unsigned short*)(bsum + 1024);
    unsigned int* xn  = (unsigned int*)(bsum + 1024) + (nE + 1) / 2;
    unsigned int* h1s = xn + (size_t)n * 16;
    int* degO   = (int*)(h1s + (size_t)n * 32);
    int* degI   = degO + n;
    int* rowptr = degI + n;
    int* csr    = rowptr + (n + 1);

    const int nB2 = (2 * NK2 + SCAN_CHUNK - 1) / SCAN_CHUNK;     // combined cntT scan
    const int waveBlocks = (n * 64 + 255) / 256;
    const int tfBlocks   = (n + NPB - 1) / NPB;

    // combined dst+src bucket counts -> one scan over 2*NK2 -> in-place offsets
    part_count<<<NCH, 256, 0, stream>>>(src, dst, cntT, nE, NBK, NCH, NK2);
    scan_partial<<<nB2, 256, 0, stream>>>(cntT, bsum, 2 * NK2);
    scan_offsets<<<1, 1024, 0, stream>>>(bsum, nB2, nullptr);
    scan_final<<<nB2, 256, 0, stream>>>(cntT, bsum, cntT, 2 * NK2);

    // single partition pass: packed dst pairs + src local ids (cursor scatter)
    part_scatter<<<NCH, 256, 0, stream>>>(src, dst, cntT, pairs, sloc, nE, NBK, NCH, NK2);

    // fused bucket kernels: dst side (degI+rowptr+csr), src side (degO+xn)
    bucket_build<<<NBK, 256, 0, stream>>>(pairs, cntT, degI, rowptr, csr, nE, n, NBK, NCH);
    bucket_srcside<<<NBK, 256, 0, stream>>>(sloc, cntT, x, degO, xn, nE, n, NBK, NCH, NK2);

    // layer 1: aggregate xn into d_out (scratch), dense transform -> h1s (fp16)
    gather_x2<<<waveBlocks, 256, 0, stream>>>(xn, csr, rowptr, out /*aggx*/, n);
    transform1<<<tfBlocks, 256, 0, stream>>>(out, W1, b1, degI, degO, h1s, n);

    // layer 2: aggregate h1s into d_out, dense transform in place
    gather_h2<<<waveBlocks, 256, 0, stream>>>(h1s, csr, rowptr, out, n);
    transform2<<<tfBlocks, 256, 0, stream>>>(out, W2, b2, degI, n);
}

// Round 12
// 190.977 us; speedup vs baseline: 1.0953x; 1.0543x over previous
//
#include <hip/hip_runtime.h>
#include <hip/hip_fp16.h>

constexpr int IN_FEATS = 30;
constexpr int HIDDEN   = 64;
constexpr int SCAN_CHUNK = 1024;   // elements per scan block (256 thr x 4)
constexpr int RB_BITS = 9;         // 512 nodes per bucket
constexpr int RB_MASK = (1 << RB_BITS) - 1;
constexpr int ECHUNK  = 2048;      // edges per partition block
constexpr int NPB     = 32;        // nodes per transform block
// pair packing: (dstLocal << 23) | src  — requires n < 2^23 (here n = 100000)

// ---- partition pass 1: per-chunk LDS bucket histograms for BOTH dst and src ----
__global__ __launch_bounds__(256) void part_count(
    const int* __restrict__ src, const int* __restrict__ dst,
    int* __restrict__ cntT, int nE, int NBK, int NCH, int NK2)
{
    __shared__ int binsD[256], binsS[256];
    int b = blockIdx.x, t = threadIdx.x;
    binsD[t] = 0; binsS[t] = 0;
    __syncthreads();
    int base = b * ECHUNK;
#pragma unroll
    for (int i = 0; i < ECHUNK / 256; ++i) {
        int e = base + t + i * 256;
        if (e < nE) {
            atomicAdd(&binsD[dst[e] >> RB_BITS], 1);
            atomicAdd(&binsS[src[e] >> RB_BITS], 1);
        }
    }
    __syncthreads();
    if (t < NBK) {
        cntT[t * NCH + b]       = binsD[t];
        cntT[NK2 + t * NCH + b] = binsS[t];
    }
}

// ---- multi-block exclusive scan, phase 1: per-block sums ----
__global__ __launch_bounds__(256) void scan_partial(
    const int* __restrict__ deg, int* __restrict__ blockSum, int n)
{
    __shared__ int part[256];
    int b = blockIdx.x, t = threadIdx.x;
    int base = b * SCAN_CHUNK + t * 4;
    int s = 0;
#pragma unroll
    for (int j = 0; j < 4; ++j) { int i = base + j; if (i < n) s += deg[i]; }
    part[t] = s;
    __syncthreads();
    for (int off = 1; off < 256; off <<= 1) {
        int add = (t >= off) ? part[t - off] : 0;
        __syncthreads();
        part[t] += add;
        __syncthreads();
    }
    if (t == 255) blockSum[b] = part[255];
}

// ---- phase 2: exclusive scan of block sums (1 block; nB <= 1024) ----
__global__ __launch_bounds__(1024) void scan_offsets(int* blockSum, int nB, int* totalPtr)
{
    __shared__ int part[1024];
    int t = threadIdx.x;
    int v = (t < nB) ? blockSum[t] : 0;
    part[t] = v;
    __syncthreads();
    for (int off = 1; off < 1024; off <<= 1) {
        int add = (t >= off) ? part[t - off] : 0;
        __syncthreads();
        part[t] += add;
        __syncthreads();
    }
    if (t < nB) blockSum[t] = part[t] - v;   // exclusive block offset
    if (totalPtr && t == nB - 1) *totalPtr = part[t];
}

// ---- phase 3: rescan chunk, write exclusive start offsets ----
__global__ __launch_bounds__(256) void scan_final(
    const int* __restrict__ deg, const int* __restrict__ blockSum,
    int* __restrict__ outp, int n)
{
    __shared__ int part[256];
    int b = blockIdx.x, t = threadIdx.x;
    int base = b * SCAN_CHUNK + t * 4;
    int v[4];
    int s = 0;
#pragma unroll
    for (int j = 0; j < 4; ++j) { int i = base + j; v[j] = (i < n) ? deg[i] : 0; s += v[j]; }
    part[t] = s;
    __syncthreads();
    for (int off = 1; off < 256; off <<= 1) {
        int add = (t >= off) ? part[t - off] : 0;
        __syncthreads();
        part[t] += add;
        __syncthreads();
    }
    int run = blockSum[b] + part[t] - s;
#pragma unroll
    for (int j = 0; j < 4; ++j) {
        int i = base + j;
        if (i < n) outp[i] = run;
        run += v[j];
    }
}

// ---- partition pass 2 (merged): dst LDS counting sort -> packed pairs (coalesced),
//      plus src scatter -> 16-bit local ids. Reads src/dst exactly once. ----
__global__ __launch_bounds__(256) void part_scatter(
    const int* __restrict__ src, const int* __restrict__ dst,
    const int* __restrict__ ofsT, unsigned int* __restrict__ pairs,
    unsigned short* __restrict__ sloc, int nE, int NBK, int NCH, int NK2)
{
    __shared__ int bins[256], lstart[256], lcur[256], gofs[256], part[256], scur[256];
    __shared__ int lsrc[ECHUNK], ldst[ECHUNK];
    int b = blockIdx.x, t = threadIdx.x;
    bins[t] = 0;
    if (t < NBK) {
        gofs[t] = ofsT[t * NCH + b];
        scur[t] = ofsT[NK2 + t * NCH + b] - nE;   // src offsets live at [nE..2nE)
    }
    __syncthreads();
    int base = b * ECHUNK;
    int rs[ECHUNK / 256], rd[ECHUNK / 256];
#pragma unroll
    for (int i = 0; i < ECHUNK / 256; ++i) {
        int e = base + t + i * 256;
        rs[i] = -1;
        if (e < nE) {
            rs[i] = src[e]; rd[i] = dst[e];
            atomicAdd(&bins[rd[i] >> RB_BITS], 1);
        }
    }
    // src-side scatter (independent of dst sort; scur init'd before first sync)
#pragma unroll
    for (int i = 0; i < ECHUNK / 256; ++i) {
        if (rs[i] >= 0) {
            int s = rs[i];
            int pos = atomicAdd(&scur[s >> RB_BITS], 1);
            sloc[pos] = (unsigned short)(s & RB_MASK);
        }
    }
    __syncthreads();
    int v = bins[t];
    part[t] = v;
    __syncthreads();
    for (int off = 1; off < 256; off <<= 1) {
        int add = (t >= off) ? part[t - off] : 0;
        __syncthreads();
        part[t] += add;
        __syncthreads();
    }
    lstart[t] = part[t] - v;
    lcur[t]   = part[t] - v;
    __syncthreads();
#pragma unroll
    for (int i = 0; i < ECHUNK / 256; ++i) {
        if (rs[i] >= 0) {
            int k = rd[i] >> RB_BITS;
            int p = atomicAdd(&lcur[k], 1);
            lsrc[p] = rs[i]; ldst[p] = rd[i];
        }
    }
    __syncthreads();
    int cE = min(ECHUNK, nE - base);
    for (int j = t; j < cE; j += 256) {
        int d = ldst[j], k = d >> RB_BITS;
        int g = gofs[k] + (j - lstart[k]);
        pairs[g] = ((unsigned int)(d & RB_MASK) << 23) | (unsigned int)lsrc[j];
    }
}

// ---- fused per-bucket build: dst hist -> scan -> degI/rowptr -> csr scatter,
//      PLUS src hist -> degO + xn pack. One block per bucket. ----
__global__ __launch_bounds__(256) void bucket_fused(
    const unsigned int* __restrict__ pairs, const unsigned short* __restrict__ sloc,
    const int* __restrict__ ofsT, const float* __restrict__ x,
    int* __restrict__ degI, int* __restrict__ rowptr, int* __restrict__ csr,
    int* __restrict__ degO, unsigned int* __restrict__ xn,
    int nE, int n, int NBK, int NCH, int NK2)
{
    __shared__ int binsD[512], binsS[512];
    __shared__ int part[256];
    __shared__ int cur[512];
    int k = blockIdx.x, t = threadIdx.x;
    binsD[t] = 0; binsD[t + 256] = 0;
    binsS[t] = 0; binsS[t + 256] = 0;
    __syncthreads();
    int beginD = ofsT[k * NCH];
    int endD   = (k + 1 < NBK) ? ofsT[(k + 1) * NCH] : nE;
    for (int e = beginD + t; e < endD; e += 256)
        atomicAdd(&binsD[pairs[e] >> 23], 1);
    int beginS = ofsT[NK2 + k * NCH] - nE;
    int endS   = (k + 1 < NBK) ? (ofsT[NK2 + (k + 1) * NCH] - nE) : nE;
    for (int e = beginS + t; e < endS; e += 256)
        atomicAdd(&binsS[sloc[e]], 1);
    __syncthreads();
    // dst side: in-bucket exclusive scan (2 bins/thread)
    int v0 = binsD[2 * t], v1 = binsD[2 * t + 1];
    int s = v0 + v1;
    part[t] = s;
    __syncthreads();
    for (int off = 1; off < 256; off <<= 1) {
        int add = (t >= off) ? part[t - off] : 0;
        __syncthreads();
        part[t] += add;
        __syncthreads();
    }
    int pre = part[t] - s;
    int base = k << RB_BITS;
    int n0 = base + 2 * t, n1 = n0 + 1;
    int r0 = beginD + pre, r1 = r0 + v0;
    cur[2 * t] = r0; cur[2 * t + 1] = r1;
    if (n0 < n) { degI[n0] = v0; rowptr[n0] = r0; }
    if (n1 < n) { degI[n1] = v1; rowptr[n1] = r1; }
    if (k == NBK - 1 && t == 0) rowptr[n] = nE;
    // src side: degO write (binsS final after the sync above)
    if (base + t < n)       degO[base + t]       = binsS[t];
    if (base + 256 + t < n) degO[base + 256 + t] = binsS[t + 256];
    __syncthreads();
    // csr scatter (L2-resident region per bucket)
    for (int e = beginD + t; e < endD; e += 256) {
        unsigned int u = pairs[e];
        int p = atomicAdd(&cur[u >> 23], 1);
        csr[p] = (int)(u & 0x7FFFFFu);
    }
    // xn pack: 512 nodes x 16 half2 words, ns from binsS
#pragma unroll 4
    for (int i = 0; i < 32; ++i) {
        int idx = t + 256 * i;             // 0..8191
        int nl = idx >> 4, p = idx & 15;
        int node = base + nl;
        if (node < n) {
            float nsv = rsqrtf(fmaxf((float)binsS[nl], 1.0f));
            float a = (2 * p     < IN_FEATS) ? x[(size_t)node * IN_FEATS + 2 * p]     * nsv : 0.0f;
            float b = (2 * p + 1 < IN_FEATS) ? x[(size_t)node * IN_FEATS + 2 * p + 1] * nsv : 0.0f;
            __half2 h = __floats2half2_rn(a, b);
            xn[(size_t)node * 16 + p] = *reinterpret_cast<unsigned int*>(&h);
        }
    }
}

// ---- layer-1 aggregation: 16 edge slots/wave, uint4 loads (64 B row), 2x unroll ----
__global__ __launch_bounds__(256) void gather_x2(
    const unsigned int* __restrict__ xn, const int* __restrict__ csr,
    const int* __restrict__ rowptr, float* __restrict__ aggx, int n)
{
    int wv   = (blockIdx.x * 256 + threadIdx.x) >> 6;
    int lane = threadIdx.x & 63;
    if (wv >= n) return;
    int begin = rowptr[wv], end = rowptr[wv + 1];
    int g = lane >> 2;        // edge slot 0..15
    int p = lane & 3;         // uint4 index (feat pairs 4p..4p+3)
    float a0 = 0, a1 = 0, a2 = 0, a3 = 0, a4 = 0, a5 = 0, a6 = 0, a7 = 0;
    int e = begin + g;
    for (; e + 16 < end; e += 32) {
        int s0 = csr[e], s1 = csr[e + 16];
        uint4 u0 = *reinterpret_cast<const uint4*>(xn + (size_t)s0 * 16 + 4 * p);
        uint4 u1 = *reinterpret_cast<const uint4*>(xn + (size_t)s1 * 16 + 4 * p);
        float2 v;
        v = __half22float2(*reinterpret_cast<__half2*>(&u0.x)); a0 += v.x; a1 += v.y;
        v = __half22float2(*reinterpret_cast<__half2*>(&u0.y)); a2 += v.x; a3 += v.y;
        v = __half22float2(*reinterpret_cast<__half2*>(&u0.z)); a4 += v.x; a5 += v.y;
        v = __half22float2(*reinterpret_cast<__half2*>(&u0.w)); a6 += v.x; a7 += v.y;
        v = __half22float2(*reinterpret_cast<__half2*>(&u1.x)); a0 += v.x; a1 += v.y;
        v = __half22float2(*reinterpret_cast<__half2*>(&u1.y)); a2 += v.x; a3 += v.y;
        v = __half22float2(*reinterpret_cast<__half2*>(&u1.z)); a4 += v.x; a5 += v.y;
        v = __half22float2(*reinterpret_cast<__half2*>(&u1.w)); a6 += v.x; a7 += v.y;
    }
    if (e < end) {
        int s0 = csr[e];
        uint4 u0 = *reinterpret_cast<const uint4*>(xn + (size_t)s0 * 16 + 4 * p);
        float2 v;
        v = __half22float2(*reinterpret_cast<__half2*>(&u0.x)); a0 += v.x; a1 += v.y;
        v = __half22float2(*reinterpret_cast<__half2*>(&u0.y)); a2 += v.x; a3 += v.y;
        v = __half22float2(*reinterpret_cast<__half2*>(&u0.z)); a4 += v.x; a5 += v.y;
        v = __half22float2(*reinterpret_cast<__half2*>(&u0.w)); a6 += v.x; a7 += v.y;
    }
#pragma unroll
    for (int m = 4; m <= 32; m <<= 1) {
        a0 += __shfl_xor(a0, m); a1 += __shfl_xor(a1, m);
        a2 += __shfl_xor(a2, m); a3 += __shfl_xor(a3, m);
        a4 += __shfl_xor(a4, m); a5 += __shfl_xor(a5, m);
        a6 += __shfl_xor(a6, m); a7 += __shfl_xor(a7, m);
    }
    if (g == 0) {
        *reinterpret_cast<float4*>(aggx + (size_t)wv * 32 + 8 * p)     = make_float4(a0, a1, a2, a3);
        *reinterpret_cast<float4*>(aggx + (size_t)wv * 32 + 8 * p + 4) = make_float4(a4, a5, a6, a7);
    }
}

// ---- layer-1 dense, register-blocked: 32 nodes/block, 8 acc/thread ----
__global__ __launch_bounds__(256) void transform1(
    const float* __restrict__ aggx, const float* __restrict__ W1,
    const float* __restrict__ b1, const int* __restrict__ degI,
    const int* __restrict__ degO, unsigned int* __restrict__ h1s, int n)
{
    __shared__ float w[32 * HIDDEN];       // 8 KB, rows 30..31 zero
    __shared__ float rows[NPB][32];        // 4 KB
    int t = threadIdx.x;
    int node0 = blockIdx.x * NPB;
    {
        const float4* w4 = (const float4*)W1;
        float4* lw4 = (float4*)w;
#pragma unroll
        for (int i = 0; i < 2; ++i) {
            int idx = t + 256 * i;
            if (idx < 480)      lw4[idx] = w4[idx];
            else if (idx < 512) lw4[idx] = make_float4(0.f, 0.f, 0.f, 0.f);
        }
    }
    {
        int node = node0 + (t >> 3);
        if (node < n)
            *reinterpret_cast<float4*>(&rows[t >> 3][(t & 7) * 4]) =
                *reinterpret_cast<const float4*>(aggx + (size_t)node * 32 + (t & 7) * 4);
    }
    __syncthreads();
    int f = t & 63, g = t >> 6;
    float acc[8] = {0, 0, 0, 0, 0, 0, 0, 0};
#pragma unroll 2
    for (int k = 0; k < 32; k += 4) {
        float w0 = w[(k + 0) * 64 + f], w1 = w[(k + 1) * 64 + f];
        float w2v = w[(k + 2) * 64 + f], w3 = w[(k + 3) * 64 + f];
#pragma unroll
        for (int j = 0; j < 8; ++j) {
            float4 rv = *reinterpret_cast<const float4*>(&rows[g * 8 + j][k]);
            acc[j] = fmaf(rv.x, w0, acc[j]);
            acc[j] = fmaf(rv.y, w1, acc[j]);
            acc[j] = fmaf(rv.z, w2v, acc[j]);
            acc[j] = fmaf(rv.w, w3, acc[j]);
        }
    }
    float bv = b1[f];
#pragma unroll
    for (int j = 0; j < 8; ++j) {
        int node = node0 + g * 8 + j;
        float hv = 0.0f;
        if (node < n) {
            float ndv = rsqrtf(fmaxf((float)degI[node], 1.0f));
            float nsv = rsqrtf(fmaxf((float)degO[node], 1.0f));
            hv = fmaxf(fmaf(acc[j], ndv, bv), 0.0f) * nsv;
        }
        float hv1 = __shfl_down(hv, 1);
        if (node < n && (f & 1) == 0) {
            __half2 h = __floats2half2_rn(hv, hv1);
            h1s[(size_t)node * 32 + (f >> 1)] = *reinterpret_cast<unsigned int*>(&h);
        }
    }
}

// ---- layer-2 aggregation: 8 edge slots/wave, uint4 loads (128 B row), 2x unroll ----
__global__ __launch_bounds__(256) void gather_h2(
    const unsigned int* __restrict__ h, const int* __restrict__ csr,
    const int* __restrict__ rowptr, float* __restrict__ agg, int n)
{
    int wv   = (blockIdx.x * 256 + threadIdx.x) >> 6;
    int lane = threadIdx.x & 63;
    if (wv >= n) return;
    int begin = rowptr[wv], end = rowptr[wv + 1];
    int g = lane >> 3;        // edge slot 0..7
    int p = lane & 7;         // uint4 index (feat pairs 4p..4p+3)
    float a0 = 0, a1 = 0, a2 = 0, a3 = 0, a4 = 0, a5 = 0, a6 = 0, a7 = 0;
    int e = begin + g;
    for (; e + 8 < end; e += 16) {
        int s0 = csr[e], s1 = csr[e + 8];
        uint4 u0 = *reinterpret_cast<const uint4*>(h + (size_t)s0 * 32 + 4 * p);
        uint4 u1 = *reinterpret_cast<const uint4*>(h + (size_t)s1 * 32 + 4 * p);
        float2 v;
        v = __half22float2(*reinterpret_cast<__half2*>(&u0.x)); a0 += v.x; a1 += v.y;
        v = __half22float2(*reinterpret_cast<__half2*>(&u0.y)); a2 += v.x; a3 += v.y;
        v = __half22float2(*reinterpret_cast<__half2*>(&u0.z)); a4 += v.x; a5 += v.y;
        v = __half22float2(*reinterpret_cast<__half2*>(&u0.w)); a6 += v.x; a7 += v.y;
        v = __half22float2(*reinterpret_cast<__half2*>(&u1.x)); a0 += v.x; a1 += v.y;
        v = __half22float2(*reinterpret_cast<__half2*>(&u1.y)); a2 += v.x; a3 += v.y;
        v = __half22float2(*reinterpret_cast<__half2*>(&u1.z)); a4 += v.x; a5 += v.y;
        v = __half22float2(*reinterpret_cast<__half2*>(&u1.w)); a6 += v.x; a7 += v.y;
    }
    if (e < end) {
        int s0 = csr[e];
        uint4 u0 = *reinterpret_cast<const uint4*>(h + (size_t)s0 * 32 + 4 * p);
        float2 v;
        v = __half22float2(*reinterpret_cast<__half2*>(&u0.x)); a0 += v.x; a1 += v.y;
        v = __half22float2(*reinterpret_cast<__half2*>(&u0.y)); a2 += v.x; a3 += v.y;
        v = __half22float2(*reinterpret_cast<__half2*>(&u0.z)); a4 += v.x; a5 += v.y;
        v = __half22float2(*reinterpret_cast<__half2*>(&u0.w)); a6 += v.x; a7 += v.y;
    }
#pragma unroll
    for (int m = 8; m <= 32; m <<= 1) {
        a0 += __shfl_xor(a0, m); a1 += __shfl_xor(a1, m);
        a2 += __shfl_xor(a2, m); a3 += __shfl_xor(a3, m);
        a4 += __shfl_xor(a4, m); a5 += __shfl_xor(a5, m);
        a6 += __shfl_xor(a6, m); a7 += __shfl_xor(a7, m);
    }
    if (g == 0) {
        *reinterpret_cast<float4*>(agg + (size_t)wv * 64 + 8 * p)     = make_float4(a0, a1, a2, a3);
        *reinterpret_cast<float4*>(agg + (size_t)wv * 64 + 8 * p + 4) = make_float4(a4, a5, a6, a7);
    }
}

// ---- layer-2 dense, register-blocked, in place on d_out ----
__global__ __launch_bounds__(256) void transform2(
    float* aggout, const float* __restrict__ W2,
    const float* __restrict__ b2, const int* __restrict__ degI, int n)
{
    __shared__ float w[HIDDEN * HIDDEN];   // 16 KB
    __shared__ float rows[NPB][HIDDEN];    // 8 KB
    int t = threadIdx.x;
    int node0 = blockIdx.x * NPB;
    {
        const float4* w4 = (const float4*)W2;
        float4* lw4 = (float4*)w;
#pragma unroll
        for (int i = 0; i < 4; ++i) lw4[t + 256 * i] = w4[t + 256 * i];
    }
    {
#pragma unroll
        for (int i = 0; i < 2; ++i) {
            int idx = t + 256 * i;
            int node = node0 + (idx >> 4);
            if (node < n)
                *reinterpret_cast<float4*>(&rows[idx >> 4][(idx & 15) * 4]) =
                    *reinterpret_cast<const float4*>(aggout + (size_t)node * 64 + (idx & 15) * 4);
        }
    }
    __syncthreads();
    int f = t & 63, g = t >> 6;
    float acc[8] = {0, 0, 0, 0, 0, 0, 0, 0};
#pragma unroll 2
    for (int k = 0; k < 64; k += 4) {
        float w0 = w[(k + 0) * 64 + f], w1 = w[(k + 1) * 64 + f];
        float w2v = w[(k + 2) * 64 + f], w3 = w[(k + 3) * 64 + f];
#pragma unroll
        for (int j = 0; j < 8; ++j) {
            float4 rv = *reinterpret_cast<const float4*>(&rows[g * 8 + j][k]);
            acc[j] = fmaf(rv.x, w0, acc[j]);
            acc[j] = fmaf(rv.y, w1, acc[j]);
            acc[j] = fmaf(rv.z, w2v, acc[j]);
            acc[j] = fmaf(rv.w, w3, acc[j]);
        }
    }
    float bv = b2[f];
#pragma unroll
    for (int j = 0; j < 8; ++j) {
        int node = node0 + g * 8 + j;
        if (node < n) {
            float ndv = rsqrtf(fmaxf((float)degI[node], 1.0f));
            aggout[(size_t)node * 64 + f] = fmaxf(fmaf(acc[j], ndv, bv), 0.0f);
        }
    }
}

extern "C" void kernel_launch(void* const* d_in, const int* in_sizes, int n_in,
                              void* d_out, int out_size, void* d_ws, size_t ws_size,
                              hipStream_t stream)
{
    const float* x  = (const float*)d_in[0];
    const float* W1 = (const float*)d_in[1];
    const float* b1 = (const float*)d_in[2];
    const float* W2 = (const float*)d_in[3];
    const float* b2 = (const float*)d_in[4];
    const int*  src = (const int*)d_in[5];
    const int*  dst = (const int*)d_in[6];
    float* out = (float*)d_out;

    const int n  = in_sizes[0] / IN_FEATS;   // 100000
    const int nE = in_sizes[5];              // 1200000

    const int NBK = (n + (1 << RB_BITS) - 1) >> RB_BITS;     // 196 buckets (<=256)
    const int NCH = (nE + ECHUNK - 1) / ECHUNK;              // 586 chunks
    const int NK2 = NBK * NCH;

    // workspace layout (non-aliased, ~33 MB):
    // pairs[nE] | cntT[2*NK2] | bsum[1024] | sloc[nE u16] | xn[n*16] | h1s[n*32] |
    // degO[n] | degI[n] | rowptr[n+1] | csr[nE]
    unsigned int* pairs = (unsigned int*)d_ws;
    int* cntT = (int*)d_ws + nE;
    int* bsum = cntT + 2 * NK2;
    unsigned short* sloc = (unsigned short*)(bsum + 1024);
    unsigned int* xn  = (unsigned int*)(bsum + 1024) + (nE + 1) / 2;
    unsigned int* h1s = xn + (size_t)n * 16;
    int* degO   = (int*)(h1s + (size_t)n * 32);
    int* degI   = degO + n;
    int* rowptr = degI + n;
    int* csr    = rowptr + (n + 1);

    const int nB2 = (2 * NK2 + SCAN_CHUNK - 1) / SCAN_CHUNK;     // combined cntT scan
    const int waveBlocks = (n * 64 + 255) / 256;
    const int tfBlocks   = (n + NPB - 1) / NPB;

    // combined dst+src bucket counts -> one scan over 2*NK2 -> in-place offsets
    part_count<<<NCH, 256, 0, stream>>>(src, dst, cntT, nE, NBK, NCH, NK2);
    scan_partial<<<nB2, 256, 0, stream>>>(cntT, bsum, 2 * NK2);
    scan_offsets<<<1, 1024, 0, stream>>>(bsum, nB2, nullptr);
    scan_final<<<nB2, 256, 0, stream>>>(cntT, bsum, cntT, 2 * NK2);

    // single partition pass: coalesced packed dst pairs (counting sort) + src local ids
    part_scatter<<<NCH, 256, 0, stream>>>(src, dst, cntT, pairs, sloc, nE, NBK, NCH, NK2);

    // fused per-bucket build: degI/rowptr/csr (dst side) + degO/xn (src side)
    bucket_fused<<<NBK, 256, 0, stream>>>(pairs, sloc, cntT, x, degI, rowptr, csr,
                                          degO, xn, nE, n, NBK, NCH, NK2);

    // layer 1: aggregate xn into d_out (scratch), dense transform -> h1s (fp16)
    gather_x2<<<waveBlocks, 256, 0, stream>>>(xn, csr, rowptr, out /*aggx*/, n);
    transform1<<<tfBlocks, 256, 0, stream>>>(out, W1, b1, degI, degO, h1s, n);

    // layer 2: aggregate h1s into d_out, dense transform in place
    gather_h2<<<waveBlocks, 256, 0, stream>>>(h1s, csr, rowptr, out, n);
    transform2<<<tfBlocks, 256, 0, stream>>>(out, W2, b2, degI, n);
}

// Round 13
// 170.352 us; speedup vs baseline: 1.2279x; 1.1211x over previous
//
#include <hip/hip_runtime.h>
#include <hip/hip_fp16.h>

constexpr int IN_FEATS = 30;
constexpr int HIDDEN   = 64;
constexpr int SCAN_CHUNK = 1024;   // elements per scan block (256 thr x 4)
constexpr int RB_BITS = 9;         // 512 nodes per bucket
constexpr int RB_MASK = (1 << RB_BITS) - 1;
constexpr int ECHUNK  = 2048;      // edges per partition block
constexpr int NPB     = 32;        // nodes per transform block
// pair packing: (dstLocal << 23) | src  — requires n < 2^23 (here n = 100000)

// ---- partition pass 1: per-chunk LDS bucket histograms for BOTH dst and src ----
__global__ __launch_bounds__(256) void part_count(
    const int* __restrict__ src, const int* __restrict__ dst,
    int* __restrict__ cntT, int nE, int NBK, int NCH, int NK2)
{
    __shared__ int binsD[256], binsS[256];
    int b = blockIdx.x, t = threadIdx.x;
    binsD[t] = 0; binsS[t] = 0;
    __syncthreads();
    int base = b * ECHUNK;
#pragma unroll
    for (int i = 0; i < ECHUNK / 256; ++i) {
        int e = base + t + i * 256;
        if (e < nE) {
            atomicAdd(&binsD[dst[e] >> RB_BITS], 1);
            atomicAdd(&binsS[src[e] >> RB_BITS], 1);
        }
    }
    __syncthreads();
    if (t < NBK) {
        cntT[t * NCH + b]       = binsD[t];
        cntT[NK2 + t * NCH + b] = binsS[t];
    }
}

// ---- multi-block exclusive scan, phase 1: per-block sums ----
__global__ __launch_bounds__(256) void scan_partial(
    const int* __restrict__ deg, int* __restrict__ blockSum, int n)
{
    __shared__ int part[256];
    int b = blockIdx.x, t = threadIdx.x;
    int base = b * SCAN_CHUNK + t * 4;
    int s = 0;
#pragma unroll
    for (int j = 0; j < 4; ++j) { int i = base + j; if (i < n) s += deg[i]; }
    part[t] = s;
    __syncthreads();
    for (int off = 1; off < 256; off <<= 1) {
        int add = (t >= off) ? part[t - off] : 0;
        __syncthreads();
        part[t] += add;
        __syncthreads();
    }
    if (t == 255) blockSum[b] = part[255];
}

// ---- phase 2: exclusive scan of block sums (1 block; nB <= 1024) ----
__global__ __launch_bounds__(1024) void scan_offsets(int* blockSum, int nB, int* totalPtr)
{
    __shared__ int part[1024];
    int t = threadIdx.x;
    int v = (t < nB) ? blockSum[t] : 0;
    part[t] = v;
    __syncthreads();
    for (int off = 1; off < 1024; off <<= 1) {
        int add = (t >= off) ? part[t - off] : 0;
        __syncthreads();
        part[t] += add;
        __syncthreads();
    }
    if (t < nB) blockSum[t] = part[t] - v;   // exclusive block offset
    if (totalPtr && t == nB - 1) *totalPtr = part[t];
}

// ---- phase 3: rescan chunk, write exclusive start offsets ----
__global__ __launch_bounds__(256) void scan_final(
    const int* __restrict__ deg, const int* __restrict__ blockSum,
    int* __restrict__ outp, int n)
{
    __shared__ int part[256];
    int b = blockIdx.x, t = threadIdx.x;
    int base = b * SCAN_CHUNK + t * 4;
    int v[4];
    int s = 0;
#pragma unroll
    for (int j = 0; j < 4; ++j) { int i = base + j; v[j] = (i < n) ? deg[i] : 0; s += v[j]; }
    part[t] = s;
    __syncthreads();
    for (int off = 1; off < 256; off <<= 1) {
        int add = (t >= off) ? part[t - off] : 0;
        __syncthreads();
        part[t] += add;
        __syncthreads();
    }
    int run = blockSum[b] + part[t] - s;
#pragma unroll
    for (int j = 0; j < 4; ++j) {
        int i = base + j;
        if (i < n) outp[i] = run;
        run += v[j];
    }
}

// ---- partition pass 2 (merged): dst LDS counting sort -> packed pairs (coalesced),
//      plus src scatter -> 16-bit local ids. Reads src/dst exactly once. ----
__global__ __launch_bounds__(256) void part_scatter(
    const int* __restrict__ src, const int* __restrict__ dst,
    const int* __restrict__ ofsT, unsigned int* __restrict__ pairs,
    unsigned short* __restrict__ sloc, int nE, int NBK, int NCH, int NK2)
{
    __shared__ int bins[256], lstart[256], lcur[256], gofs[256], part[256], scur[256];
    __shared__ int lsrc[ECHUNK], ldst[ECHUNK];
    int b = blockIdx.x, t = threadIdx.x;
    bins[t] = 0;
    if (t < NBK) {
        gofs[t] = ofsT[t * NCH + b];
        scur[t] = ofsT[NK2 + t * NCH + b] - nE;   // src offsets live at [nE..2nE)
    }
    __syncthreads();
    int base = b * ECHUNK;
    int rs[ECHUNK / 256], rd[ECHUNK / 256];
#pragma unroll
    for (int i = 0; i < ECHUNK / 256; ++i) {
        int e = base + t + i * 256;
        rs[i] = -1;
        if (e < nE) {
            rs[i] = src[e]; rd[i] = dst[e];
            atomicAdd(&bins[rd[i] >> RB_BITS], 1);
        }
    }
    // src-side scatter (independent of dst sort; scur init'd before first sync)
#pragma unroll
    for (int i = 0; i < ECHUNK / 256; ++i) {
        if (rs[i] >= 0) {
            int s = rs[i];
            int pos = atomicAdd(&scur[s >> RB_BITS], 1);
            sloc[pos] = (unsigned short)(s & RB_MASK);
        }
    }
    __syncthreads();
    int v = bins[t];
    part[t] = v;
    __syncthreads();
    for (int off = 1; off < 256; off <<= 1) {
        int add = (t >= off) ? part[t - off] : 0;
        __syncthreads();
        part[t] += add;
        __syncthreads();
    }
    lstart[t] = part[t] - v;
    lcur[t]   = part[t] - v;
    __syncthreads();
#pragma unroll
    for (int i = 0; i < ECHUNK / 256; ++i) {
        if (rs[i] >= 0) {
            int k = rd[i] >> RB_BITS;
            int p = atomicAdd(&lcur[k], 1);
            lsrc[p] = rs[i]; ldst[p] = rd[i];
        }
    }
    __syncthreads();
    int cE = min(ECHUNK, nE - base);
    for (int j = t; j < cE; j += 256) {
        int d = ldst[j], k = d >> RB_BITS;
        int g = gofs[k] + (j - lstart[k]);
        pairs[g] = ((unsigned int)(d & RB_MASK) << 23) | (unsigned int)lsrc[j];
    }
}

// ---- fused per-bucket build, WIDE block (1024 thr = 16 waves for latency hiding):
//      dst hist -> scan -> degI/rowptr -> csr scatter, PLUS src hist -> degO + xn. ----
__global__ __launch_bounds__(1024) void bucket_fused(
    const unsigned int* __restrict__ pairs, const unsigned short* __restrict__ sloc,
    const int* __restrict__ ofsT, const float* __restrict__ x,
    int* __restrict__ degI, int* __restrict__ rowptr, int* __restrict__ csr,
    int* __restrict__ degO, unsigned int* __restrict__ xn,
    int nE, int n, int NBK, int NCH, int NK2)
{
    __shared__ int binsD[512], binsS[512];
    __shared__ int part[512];
    __shared__ int cur[512];
    int k = blockIdx.x, t = threadIdx.x;
    if (t < 512) { binsD[t] = 0; binsS[t] = 0; }
    __syncthreads();
    int beginD = ofsT[k * NCH];
    int endD   = (k + 1 < NBK) ? ofsT[(k + 1) * NCH] : nE;
    for (int e = beginD + t; e < endD; e += 1024)
        atomicAdd(&binsD[pairs[e] >> 23], 1);
    int beginS = ofsT[NK2 + k * NCH] - nE;
    int endS   = (k + 1 < NBK) ? (ofsT[NK2 + (k + 1) * NCH] - nE) : nE;
    for (int e = beginS + t; e < endS; e += 1024)
        atomicAdd(&binsS[sloc[e]], 1);
    __syncthreads();
    // in-bucket exclusive scan over 512 dst bins, 1 bin/thread (t < 512)
    int v = (t < 512) ? binsD[t] : 0;
    if (t < 512) part[t] = v;
    __syncthreads();
    for (int off = 1; off < 512; off <<= 1) {
        int add = (t >= off && t < 512) ? part[t - off] : 0;
        __syncthreads();
        if (t < 512) part[t] += add;
        __syncthreads();
    }
    int base = k << RB_BITS;
    if (t < 512) {
        int pre = part[t] - v;          // exclusive prefix within bucket
        int node = base + t;
        int r0 = beginD + pre;
        cur[t] = r0;
        if (node < n) {
            degI[node]   = v;
            rowptr[node] = r0;
            degO[node]   = binsS[t];
        }
    }
    if (k == NBK - 1 && t == 0) rowptr[n] = nE;
    __syncthreads();
    // csr scatter (L2-resident region per bucket)
    for (int e = beginD + t; e < endD; e += 1024) {
        unsigned int u = pairs[e];
        int p = atomicAdd(&cur[u >> 23], 1);
        csr[p] = (int)(u & 0x7FFFFFu);
    }
    // xn pack: 512 nodes x 16 half2 words = 8192, 8 per thread
#pragma unroll
    for (int i = 0; i < 8; ++i) {
        int idx = t + 1024 * i;            // 0..8191
        int nl = idx >> 4, p = idx & 15;
        int node = base + nl;
        if (node < n) {
            float nsv = rsqrtf(fmaxf((float)binsS[nl], 1.0f));
            float a = (2 * p     < IN_FEATS) ? x[(size_t)node * IN_FEATS + 2 * p]     * nsv : 0.0f;
            float b = (2 * p + 1 < IN_FEATS) ? x[(size_t)node * IN_FEATS + 2 * p + 1] * nsv : 0.0f;
            __half2 h = __floats2half2_rn(a, b);
            xn[(size_t)node * 16 + p] = *reinterpret_cast<unsigned int*>(&h);
        }
    }
}

// ---- layer-1 aggregation: 16 edge slots/wave, uint4 loads (64 B row), 2x unroll ----
__global__ __launch_bounds__(256) void gather_x2(
    const unsigned int* __restrict__ xn, const int* __restrict__ csr,
    const int* __restrict__ rowptr, float* __restrict__ aggx, int n)
{
    int wv   = (blockIdx.x * 256 + threadIdx.x) >> 6;
    int lane = threadIdx.x & 63;
    if (wv >= n) return;
    int begin = rowptr[wv], end = rowptr[wv + 1];
    int g = lane >> 2;        // edge slot 0..15
    int p = lane & 3;         // uint4 index (feat pairs 4p..4p+3)
    float a0 = 0, a1 = 0, a2 = 0, a3 = 0, a4 = 0, a5 = 0, a6 = 0, a7 = 0;
    int e = begin + g;
    for (; e + 16 < end; e += 32) {
        int s0 = csr[e], s1 = csr[e + 16];
        uint4 u0 = *reinterpret_cast<const uint4*>(xn + (size_t)s0 * 16 + 4 * p);
        uint4 u1 = *reinterpret_cast<const uint4*>(xn + (size_t)s1 * 16 + 4 * p);
        float2 v;
        v = __half22float2(*reinterpret_cast<__half2*>(&u0.x)); a0 += v.x; a1 += v.y;
        v = __half22float2(*reinterpret_cast<__half2*>(&u0.y)); a2 += v.x; a3 += v.y;
        v = __half22float2(*reinterpret_cast<__half2*>(&u0.z)); a4 += v.x; a5 += v.y;
        v = __half22float2(*reinterpret_cast<__half2*>(&u0.w)); a6 += v.x; a7 += v.y;
        v = __half22float2(*reinterpret_cast<__half2*>(&u1.x)); a0 += v.x; a1 += v.y;
        v = __half22float2(*reinterpret_cast<__half2*>(&u1.y)); a2 += v.x; a3 += v.y;
        v = __half22float2(*reinterpret_cast<__half2*>(&u1.z)); a4 += v.x; a5 += v.y;
        v = __half22float2(*reinterpret_cast<__half2*>(&u1.w)); a6 += v.x; a7 += v.y;
    }
    if (e < end) {
        int s0 = csr[e];
        uint4 u0 = *reinterpret_cast<const uint4*>(xn + (size_t)s0 * 16 + 4 * p);
        float2 v;
        v = __half22float2(*reinterpret_cast<__half2*>(&u0.x)); a0 += v.x; a1 += v.y;
        v = __half22float2(*reinterpret_cast<__half2*>(&u0.y)); a2 += v.x; a3 += v.y;
        v = __half22float2(*reinterpret_cast<__half2*>(&u0.z)); a4 += v.x; a5 += v.y;
        v = __half22float2(*reinterpret_cast<__half2*>(&u0.w)); a6 += v.x; a7 += v.y;
    }
#pragma unroll
    for (int m = 4; m <= 32; m <<= 1) {
        a0 += __shfl_xor(a0, m); a1 += __shfl_xor(a1, m);
        a2 += __shfl_xor(a2, m); a3 += __shfl_xor(a3, m);
        a4 += __shfl_xor(a4, m); a5 += __shfl_xor(a5, m);
        a6 += __shfl_xor(a6, m); a7 += __shfl_xor(a7, m);
    }
    if (g == 0) {
        *reinterpret_cast<float4*>(aggx + (size_t)wv * 32 + 8 * p)     = make_float4(a0, a1, a2, a3);
        *reinterpret_cast<float4*>(aggx + (size_t)wv * 32 + 8 * p + 4) = make_float4(a4, a5, a6, a7);
    }
}

// ---- layer-1 dense, register-blocked: 32 nodes/block, 8 acc/thread ----
__global__ __launch_bounds__(256) void transform1(
    const float* __restrict__ aggx, const float* __restrict__ W1,
    const float* __restrict__ b1, const int* __restrict__ degI,
    const int* __restrict__ degO, unsigned int* __restrict__ h1s, int n)
{
    __shared__ float w[32 * HIDDEN];       // 8 KB, rows 30..31 zero
    __shared__ float rows[NPB][32];        // 4 KB
    int t = threadIdx.x;
    int node0 = blockIdx.x * NPB;
    {
        const float4* w4 = (const float4*)W1;
        float4* lw4 = (float4*)w;
#pragma unroll
        for (int i = 0; i < 2; ++i) {
            int idx = t + 256 * i;
            if (idx < 480)      lw4[idx] = w4[idx];
            else if (idx < 512) lw4[idx] = make_float4(0.f, 0.f, 0.f, 0.f);
        }
    }
    {
        int node = node0 + (t >> 3);
        if (node < n)
            *reinterpret_cast<float4*>(&rows[t >> 3][(t & 7) * 4]) =
                *reinterpret_cast<const float4*>(aggx + (size_t)node * 32 + (t & 7) * 4);
    }
    __syncthreads();
    int f = t & 63, g = t >> 6;
    float acc[8] = {0, 0, 0, 0, 0, 0, 0, 0};
#pragma unroll 2
    for (int k = 0; k < 32; k += 4) {
        float w0 = w[(k + 0) * 64 + f], w1 = w[(k + 1) * 64 + f];
        float w2v = w[(k + 2) * 64 + f], w3 = w[(k + 3) * 64 + f];
#pragma unroll
        for (int j = 0; j < 8; ++j) {
            float4 rv = *reinterpret_cast<const float4*>(&rows[g * 8 + j][k]);
            acc[j] = fmaf(rv.x, w0, acc[j]);
            acc[j] = fmaf(rv.y, w1, acc[j]);
            acc[j] = fmaf(rv.z, w2v, acc[j]);
            acc[j] = fmaf(rv.w, w3, acc[j]);
        }
    }
    float bv = b1[f];
#pragma unroll
    for (int j = 0; j < 8; ++j) {
        int node = node0 + g * 8 + j;
        float hv = 0.0f;
        if (node < n) {
            float ndv = rsqrtf(fmaxf((float)degI[node], 1.0f));
            float nsv = rsqrtf(fmaxf((float)degO[node], 1.0f));
            hv = fmaxf(fmaf(acc[j], ndv, bv), 0.0f) * nsv;
        }
        float hv1 = __shfl_down(hv, 1);
        if (node < n && (f & 1) == 0) {
            __half2 h = __floats2half2_rn(hv, hv1);
            h1s[(size_t)node * 32 + (f >> 1)] = *reinterpret_cast<unsigned int*>(&h);
        }
    }
}

// ---- layer-2 aggregation: 8 edge slots/wave, uint4 loads (128 B row), 2x unroll ----
__global__ __launch_bounds__(256) void gather_h2(
    const unsigned int* __restrict__ h, const int* __restrict__ csr,
    const int* __restrict__ rowptr, float* __restrict__ agg, int n)
{
    int wv   = (blockIdx.x * 256 + threadIdx.x) >> 6;
    int lane = threadIdx.x & 63;
    if (wv >= n) return;
    int begin = rowptr[wv], end = rowptr[wv + 1];
    int g = lane >> 3;        // edge slot 0..7
    int p = lane & 7;         // uint4 index (feat pairs 4p..4p+3)
    float a0 = 0, a1 = 0, a2 = 0, a3 = 0, a4 = 0, a5 = 0, a6 = 0, a7 = 0;
    int e = begin + g;
    for (; e + 8 < end; e += 16) {
        int s0 = csr[e], s1 = csr[e + 8];
        uint4 u0 = *reinterpret_cast<const uint4*>(h + (size_t)s0 * 32 + 4 * p);
        uint4 u1 = *reinterpret_cast<const uint4*>(h + (size_t)s1 * 32 + 4 * p);
        float2 v;
        v = __half22float2(*reinterpret_cast<__half2*>(&u0.x)); a0 += v.x; a1 += v.y;
        v = __half22float2(*reinterpret_cast<__half2*>(&u0.y)); a2 += v.x; a3 += v.y;
        v = __half22float2(*reinterpret_cast<__half2*>(&u0.z)); a4 += v.x; a5 += v.y;
        v = __half22float2(*reinterpret_cast<__half2*>(&u0.w)); a6 += v.x; a7 += v.y;
        v = __half22float2(*reinterpret_cast<__half2*>(&u1.x)); a0 += v.x; a1 += v.y;
        v = __half22float2(*reinterpret_cast<__half2*>(&u1.y)); a2 += v.x; a3 += v.y;
        v = __half22float2(*reinterpret_cast<__half2*>(&u1.z)); a4 += v.x; a5 += v.y;
        v = __half22float2(*reinterpret_cast<__half2*>(&u1.w)); a6 += v.x; a7 += v.y;
    }
    if (e < end) {
        int s0 = csr[e];
        uint4 u0 = *reinterpret_cast<const uint4*>(h + (size_t)s0 * 32 + 4 * p);
        float2 v;
        v = __half22float2(*reinterpret_cast<__half2*>(&u0.x)); a0 += v.x; a1 += v.y;
        v = __half22float2(*reinterpret_cast<__half2*>(&u0.y)); a2 += v.x; a3 += v.y;
        v = __half22float2(*reinterpret_cast<__half2*>(&u0.z)); a4 += v.x; a5 += v.y;
        v = __half22float2(*reinterpret_cast<__half2*>(&u0.w)); a6 += v.x; a7 += v.y;
    }
#pragma unroll
    for (int m = 8; m <= 32; m <<= 1) {
        a0 += __shfl_xor(a0, m); a1 += __shfl_xor(a1, m);
        a2 += __shfl_xor(a2, m); a3 += __shfl_xor(a3, m);
        a4 += __shfl_xor(a4, m); a5 += __shfl_xor(a5, m);
        a6 += __shfl_xor(a6, m); a7 += __shfl_xor(a7, m);
    }
    if (g == 0) {
        *reinterpret_cast<float4*>(agg + (size_t)wv * 64 + 8 * p)     = make_float4(a0, a1, a2, a3);
        *reinterpret_cast<float4*>(agg + (size_t)wv * 64 + 8 * p + 4) = make_float4(a4, a5, a6, a7);
    }
}

// ---- layer-2 dense, register-blocked, in place on d_out ----
__global__ __launch_bounds__(256) void transform2(
    float* aggout, const float* __restrict__ W2,
    const float* __restrict__ b2, const int* __restrict__ degI, int n)
{
    __shared__ float w[HIDDEN * HIDDEN];   // 16 KB
    __shared__ float rows[NPB][HIDDEN];    // 8 KB
    int t = threadIdx.x;
    int node0 = blockIdx.x * NPB;
    {
        const float4* w4 = (const float4*)W2;
        float4* lw4 = (float4*)w;
#pragma unroll
        for (int i = 0; i < 4; ++i) lw4[t + 256 * i] = w4[t + 256 * i];
    }
    {
#pragma unroll
        for (int i = 0; i < 2; ++i) {
            int idx = t + 256 * i;
            int node = node0 + (idx >> 4);
            if (node < n)
                *reinterpret_cast<float4*>(&rows[idx >> 4][(idx & 15) * 4]) =
                    *reinterpret_cast<const float4*>(aggout + (size_t)node * 64 + (idx & 15) * 4);
        }
    }
    __syncthreads();
    int f = t & 63, g = t >> 6;
    float acc[8] = {0, 0, 0, 0, 0, 0, 0, 0};
#pragma unroll 2
    for (int k = 0; k < 64; k += 4) {
        float w0 = w[(k + 0) * 64 + f], w1 = w[(k + 1) * 64 + f];
        float w2v = w[(k + 2) * 64 + f], w3 = w[(k + 3) * 64 + f];
#pragma unroll
        for (int j = 0; j < 8; ++j) {
            float4 rv = *reinterpret_cast<const float4*>(&rows[g * 8 + j][k]);
            acc[j] = fmaf(rv.x, w0, acc[j]);
            acc[j] = fmaf(rv.y, w1, acc[j]);
            acc[j] = fmaf(rv.z, w2v, acc[j]);
            acc[j] = fmaf(rv.w, w3, acc[j]);
        }
    }
    float bv = b2[f];
#pragma unroll
    for (int j = 0; j < 8; ++j) {
        int node = node0 + g * 8 + j;
        if (node < n) {
            float ndv = rsqrtf(fmaxf((float)degI[node], 1.0f));
            aggout[(size_t)node * 64 + f] = fmaxf(fmaf(acc[j], ndv, bv), 0.0f);
        }
    }
}

extern "C" void kernel_launch(void* const* d_in, const int* in_sizes, int n_in,
                              void* d_out, int out_size, void* d_ws, size_t ws_size,
                              hipStream_t stream)
{
    const float* x  = (const float*)d_in[0];
    const float* W1 = (const float*)d_in[1];
    const float* b1 = (const float*)d_in[2];
    const float* W2 = (const float*)d_in[3];
    const float* b2 = (const float*)d_in[4];
    const int*  src = (const int*)d_in[5];
    const int*  dst = (const int*)d_in[6];
    float* out = (float*)d_out;

    const int n  = in_sizes[0] / IN_FEATS;   // 100000
    const int nE = in_sizes[5];              // 1200000

    const int NBK = (n + (1 << RB_BITS) - 1) >> RB_BITS;     // 196 buckets (<=256)
    const int NCH = (nE + ECHUNK - 1) / ECHUNK;              // 586 chunks
    const int NK2 = NBK * NCH;

    // workspace layout (non-aliased, ~33 MB):
    // pairs[nE] | cntT[2*NK2] | bsum[1024] | sloc[nE u16] | xn[n*16] | h1s[n*32] |
    // degO[n] | degI[n] | rowptr[n+1] | csr[nE]
    unsigned int* pairs = (unsigned int*)d_ws;
    int* cntT = (int*)d_ws + nE;
    int* bsum = cntT + 2 * NK2;
    unsigned short* sloc = (unsigned short*)(bsum + 1024);
    unsigned int* xn  = (unsigned int*)(bsum + 1024) + (nE + 1) / 2;
    unsigned int* h1s = xn + (size_t)n * 16;
    int* degO   = (int*)(h1s + (size_t)n * 32);
    int* degI   = degO + n;
    int* rowptr = degI + n;
    int* csr    = rowptr + (n + 1);

    const int nB2 = (2 * NK2 + SCAN_CHUNK - 1) / SCAN_CHUNK;     // combined cntT scan
    const int waveBlocks = (n * 64 + 255) / 256;
    const int tfBlocks   = (n + NPB - 1) / NPB;

    // combined dst+src bucket counts -> one scan over 2*NK2 -> in-place offsets
    part_count<<<NCH, 256, 0, stream>>>(src, dst, cntT, nE, NBK, NCH, NK2);
    scan_partial<<<nB2, 256, 0, stream>>>(cntT, bsum, 2 * NK2);
    scan_offsets<<<1, 1024, 0, stream>>>(bsum, nB2, nullptr);
    scan_final<<<nB2, 256, 0, stream>>>(cntT, bsum, cntT, 2 * NK2);

    // single partition pass: coalesced packed dst pairs (counting sort) + src local ids
    part_scatter<<<NCH, 256, 0, stream>>>(src, dst, cntT, pairs, sloc, nE, NBK, NCH, NK2);

    // fused per-bucket build (wide 1024-thread blocks): degI/rowptr/csr + degO/xn
    bucket_fused<<<NBK, 1024, 0, stream>>>(pairs, sloc, cntT, x, degI, rowptr, csr,
                                           degO, xn, nE, n, NBK, NCH, NK2);

    // layer 1: aggregate xn into d_out (scratch), dense transform -> h1s (fp16)
    gather_x2<<<waveBlocks, 256, 0, stream>>>(xn, csr, rowptr, out /*aggx*/, n);
    transform1<<<tfBlocks, 256, 0, stream>>>(out, W1, b1, degI, degO, h1s, n);

    // layer 2: aggregate h1s into d_out, dense transform in place
    gather_h2<<<waveBlocks, 256, 0, stream>>>(h1s, csr, rowptr, out, n);
    transform2<<<tfBlocks, 256, 0, stream>>>(out, W2, b2, degI, n);
}